// Round 1
// baseline (618.841 us; speedup 1.0000x reference)
//
#include <hip/hip_runtime.h>

typedef unsigned short u16;
typedef __attribute__((ext_vector_type(8))) short bf16x8;
typedef __attribute__((ext_vector_type(4))) float f32x4;

#define DEV static __device__ __forceinline__

DEV u16 f2bf(float f) {
    unsigned u = __float_as_uint(f);
    u += 0x7FFFu + ((u >> 16) & 1u);
    return (u16)(u >> 16);
}

typedef const __attribute__((address_space(1))) void* gas1_t;
typedef __attribute__((address_space(3))) void* gas3_t;

DEV void gl_lds16(const u16* g, u16* l) {
    __builtin_amdgcn_global_load_lds((gas1_t)g, (gas3_t)l, 16, 0, 0);
}

// ---------------- elementwise f32 -> bf16 cast (weights) ----------------
__global__ void cast_bf16(const float* __restrict__ in, u16* __restrict__ out, int n4) {
    int i = blockIdx.x * blockDim.x + threadIdx.x;
    if (i < n4) {
        float4 v = ((const float4*)in)[i];
        ushort4 o;
        o.x = f2bf(v.x); o.y = f2bf(v.y); o.z = f2bf(v.z); o.w = f2bf(v.w);
        ((ushort4*)out)[i] = o;
    }
}

// ---------------- LayerNorm (D=1024) f32 -> bf16 ----------------
__global__ __launch_bounds__(256) void ln_bf16(const float* __restrict__ x,
                                               const float* __restrict__ gam,
                                               const float* __restrict__ bet,
                                               u16* __restrict__ y) {
    const int row = blockIdx.x;
    const int t = threadIdx.x;
    const float4 v = ((const float4*)(x + (size_t)row * 1024))[t];
    float s = v.x + v.y + v.z + v.w;
    float ss = v.x * v.x + v.y * v.y + v.z * v.z + v.w * v.w;
#pragma unroll
    for (int o = 1; o < 64; o <<= 1) {
        s += __shfl_xor(s, o);
        ss += __shfl_xor(ss, o);
    }
    __shared__ float rs[4], rss[4];
    const int wave = t >> 6, lane = t & 63;
    if (lane == 0) { rs[wave] = s; rss[wave] = ss; }
    __syncthreads();
    const float tot = rs[0] + rs[1] + rs[2] + rs[3];
    const float totss = rss[0] + rss[1] + rss[2] + rss[3];
    const float mu = tot * (1.0f / 1024.0f);
    const float var = totss * (1.0f / 1024.0f) - mu * mu;
    const float rstd = rsqrtf(var + 1e-5f);
    const float4 g4 = ((const float4*)gam)[t];
    const float4 b4 = ((const float4*)bet)[t];
    ushort4 o;
    o.x = f2bf((v.x - mu) * rstd * g4.x + b4.x);
    o.y = f2bf((v.y - mu) * rstd * g4.y + b4.y);
    o.z = f2bf((v.z - mu) * rstd * g4.z + b4.z);
    o.w = f2bf((v.w - mu) * rstd * g4.w + b4.w);
    ((ushort4*)(y + (size_t)row * 1024))[t] = o;
}

// ---------------- GEMM: C[M,N] = A[M,K] @ Bt[N,K]^T (+epilogue) ----------------
// EPI 0: +qkv_b, scatter bf16 -> Vt[out0], Q[out1], K[out2]
// EPI 1: +res (f32), write f32 out0
// EPI 2: +bias, relu, write bf16 out0
// EPI 3: +bias +res, write f32 out0
template <int EPI>
__global__ __launch_bounds__(256, 2) void gemm_bt(const u16* __restrict__ A,
                                                  const u16* __restrict__ Bt,
                                                  const float* __restrict__ bias,
                                                  const float* __restrict__ res,
                                                  void* __restrict__ out0,
                                                  void* __restrict__ out1,
                                                  void* __restrict__ out2,
                                                  int M, int N, int K) {
    __shared__ __align__(16) u16 As[128 * 32];
    __shared__ __align__(16) u16 Bs[128 * 32];
    const int tid = threadIdx.x;
    const int wave = tid >> 6, lane = tid & 63;
    const int lhi = lane >> 4, llo = lane & 15;
    const int bx = blockIdx.x, by = blockIdx.y;

    const int arow = wave * 32 + (lane >> 2);
    const int acol = (lane & 3) * 8;
    const u16* gA = A + (size_t)(by * 128 + arow) * K + acol;
    const u16* gB = Bt + (size_t)(bx * 128 + arow) * K + acol;
    u16* lA = As + wave * 1024 + lane * 8;
    u16* lB = Bs + wave * 1024 + lane * 8;

    const int wr = wave >> 1, wc = wave & 1;
    const f32x4 zero = {0.f, 0.f, 0.f, 0.f};
    f32x4 acc[4][4];
#pragma unroll
    for (int i = 0; i < 4; i++)
#pragma unroll
        for (int j = 0; j < 4; j++) acc[i][j] = zero;

    for (int k0 = 0; k0 < K; k0 += 32) {
        __syncthreads();
        gl_lds16(gA, lA);
        gl_lds16(gA + 16 * (size_t)K, lA + 512);
        gl_lds16(gB, lB);
        gl_lds16(gB + 16 * (size_t)K, lB + 512);
        gA += 32; gB += 32;
        __syncthreads();
        bf16x8 af[4], bfr[4];
#pragma unroll
        for (int i = 0; i < 4; i++)
            af[i] = *(const bf16x8*)(As + (wr * 64 + i * 16 + llo) * 32 + lhi * 8);
#pragma unroll
        for (int j = 0; j < 4; j++)
            bfr[j] = *(const bf16x8*)(Bs + (wc * 64 + j * 16 + llo) * 32 + lhi * 8);
#pragma unroll
        for (int i = 0; i < 4; i++)
#pragma unroll
            for (int j = 0; j < 4; j++)
                acc[i][j] = __builtin_amdgcn_mfma_f32_16x16x32_bf16(af[i], bfr[j], acc[i][j], 0, 0, 0);
    }

    const int rbase = by * 128 + wr * 64 + lhi * 4;
    const int cbase = bx * 128 + wc * 64 + llo;
#pragma unroll
    for (int i = 0; i < 4; i++) {
#pragma unroll
        for (int j = 0; j < 4; j++) {
#pragma unroll
            for (int r = 0; r < 4; r++) {
                const int row = rbase + i * 16 + r;
                const int col = cbase + j * 16;
                float v = acc[i][j][r];
                if (EPI == 0) {
                    v += bias[col];
                    const int hh = col / 192;
                    const int t = col - hh * 192;
                    const int b = row >> 11, n = row & 2047;
                    const int bh = (b << 4) + hh;
                    const u16 bv = f2bf(v);
                    if (t < 64)
                        ((u16*)out0)[((size_t)bh * 64 + t) * 2048 + n] = bv;       // Vt [BH][DH][N]
                    else if (t < 128)
                        ((u16*)out1)[((size_t)bh * 2048 + n) * 64 + (t - 64)] = bv; // Q [BH][N][DH]
                    else
                        ((u16*)out2)[((size_t)bh * 2048 + n) * 64 + (t - 128)] = bv; // K [BH][N][DH]
                } else if (EPI == 1) {
                    ((float*)out0)[(size_t)row * N + col] = v + res[(size_t)row * N + col];
                } else if (EPI == 2) {
                    v += bias[col];
                    v = v > 0.f ? v : 0.f;
                    ((u16*)out0)[(size_t)row * N + col] = f2bf(v);
                } else {
                    v += bias[col] + res[(size_t)row * N + col];
                    ((float*)out0)[(size_t)row * N + col] = v;
                }
            }
        }
    }
}

// ---------------- fused flash-style attention ----------------
// grid: (N/64 q-tiles, B*H).  Per block: 64 q-rows, loop over 64-wide m-tiles.
// S = QK^T/8 + new_mask ; online softmax (denominator unmasked) ;
// P = exp(S-m)*mask ; O += P @ V ; epilogue leaky_relu(O/l) -> bf16 attnL.
__global__ __launch_bounds__(256, 2) void attn_fused(const u16* __restrict__ Qg,
                                                     const u16* __restrict__ Kg,
                                                     const u16* __restrict__ Vt,
                                                     const float* __restrict__ nmask,
                                                     const float* __restrict__ pmask,
                                                     u16* __restrict__ attnL) {
    __shared__ __align__(16) u16 Qs[64 * 64];
    __shared__ __align__(16) u16 Ks[64 * 64];
    __shared__ __align__(16) u16 Vs[64 * 64];  // [d][m]
    __shared__ __align__(16) u16 Ps[64 * 64];  // [q][m]
    const int tid = threadIdx.x, wave = tid >> 6, lane = tid & 63;
    const int lhi = lane >> 4, llo = lane & 15;
    const int qt = blockIdx.x, bh = blockIdx.y;
    const int b = bh >> 4, hh = bh & 15;
    const int q0 = qt * 64;

    {   // stage Q tile once
        const int r = lane >> 3, c = (lane & 7) * 8;
        const u16* g = Qg + ((size_t)bh * 2048 + q0 + wave * 16 + r) * 64 + c;
        gl_lds16(g, Qs + wave * 1024 + lane * 8);
        gl_lds16(g + 8 * 64, Qs + wave * 1024 + 512 + lane * 8);
    }

    const f32x4 zero = {0.f, 0.f, 0.f, 0.f};
    f32x4 accO[4];
    float m_run[4], l_run[4];
#pragma unroll
    for (int jd = 0; jd < 4; jd++) accO[jd] = zero;
#pragma unroll
    for (int r = 0; r < 4; r++) { m_run[r] = -1e30f; l_run[r] = 0.f; }

    const int qrow = q0 + wave * 16 + lhi * 4;                 // + r
    const size_t mrowbase = ((size_t)b * 2048 + qrow) * 2048;  // + r*2048 + m

    for (int m0 = 0; m0 < 2048; m0 += 64) {
        __syncthreads();
        {   // stage K rows m0..m0+63 and Vt rows (all 64 d) cols m0..m0+63
            const int r = lane >> 3, c = (lane & 7) * 8;
            const u16* gk = Kg + ((size_t)bh * 2048 + m0 + wave * 16 + r) * 64 + c;
            gl_lds16(gk, Ks + wave * 1024 + lane * 8);
            gl_lds16(gk + 512, Ks + wave * 1024 + 512 + lane * 8);
            const u16* gv = Vt + ((size_t)bh * 64 + wave * 16 + r) * 2048 + m0 + c;
            gl_lds16(gv, Vs + wave * 1024 + lane * 8);
            gl_lds16(gv + 8 * 2048, Vs + wave * 1024 + 512 + lane * 8);
        }
        __syncthreads();

        // S = Q K^T  (wave's 16 q-rows x 64 m-cols)
        f32x4 sacc[4];
#pragma unroll
        for (int j = 0; j < 4; j++) sacc[j] = zero;
#pragma unroll
        for (int kk = 0; kk < 2; kk++) {
            const bf16x8 aq = *(const bf16x8*)(Qs + (wave * 16 + llo) * 64 + kk * 32 + lhi * 8);
#pragma unroll
            for (int j = 0; j < 4; j++) {
                const bf16x8 bk = *(const bf16x8*)(Ks + (j * 16 + llo) * 64 + kk * 32 + lhi * 8);
                sacc[j] = __builtin_amdgcn_mfma_f32_16x16x32_bf16(aq, bk, sacc[j], 0, 0, 0);
            }
        }

        // scale + new_mask, row max
        float tmax[4] = {-1e30f, -1e30f, -1e30f, -1e30f};
#pragma unroll
        for (int j = 0; j < 4; j++)
#pragma unroll
            for (int r = 0; r < 4; r++) {
                const float s = sacc[j][r] * 0.125f +
                                nmask[mrowbase + (size_t)r * 2048 + m0 + j * 16 + llo];
                sacc[j][r] = s;
                tmax[r] = fmaxf(tmax[r], s);
            }
#pragma unroll
        for (int r = 0; r < 4; r++) {
#pragma unroll
            for (int o = 1; o < 16; o <<= 1) tmax[r] = fmaxf(tmax[r], __shfl_xor(tmax[r], o));
        }

        float alpha[4], lsum[4];
#pragma unroll
        for (int r = 0; r < 4; r++) {
            const float mnew = fmaxf(m_run[r], tmax[r]);
            alpha[r] = __expf(m_run[r] - mnew);
            m_run[r] = mnew;
            lsum[r] = 0.f;
        }
#pragma unroll
        for (int j = 0; j < 4; j++)
#pragma unroll
            for (int r = 0; r < 4; r++) {
                const float e = __expf(sacc[j][r] - m_run[r]);
                lsum[r] += e;
                const float p = e * pmask[mrowbase + (size_t)r * 2048 + m0 + j * 16 + llo];
                Ps[(wave * 16 + lhi * 4 + r) * 64 + j * 16 + llo] = f2bf(p);
            }
#pragma unroll
        for (int r = 0; r < 4; r++) {
#pragma unroll
            for (int o = 1; o < 16; o <<= 1) lsum[r] += __shfl_xor(lsum[r], o);
            l_run[r] = l_run[r] * alpha[r] + lsum[r];
        }
#pragma unroll
        for (int jd = 0; jd < 4; jd++)
#pragma unroll
            for (int r = 0; r < 4; r++) accO[jd][r] *= alpha[r];

        // O += P @ V   (Ps rows are wave-private; in-wave LDS ordering suffices)
#pragma unroll
        for (int kk = 0; kk < 2; kk++) {
            const bf16x8 ap = *(const bf16x8*)(Ps + (wave * 16 + llo) * 64 + kk * 32 + lhi * 8);
#pragma unroll
            for (int jd = 0; jd < 4; jd++) {
                const bf16x8 bv = *(const bf16x8*)(Vs + (jd * 16 + llo) * 64 + kk * 32 + lhi * 8);
                accO[jd] = __builtin_amdgcn_mfma_f32_16x16x32_bf16(ap, bv, accO[jd], 0, 0, 0);
            }
        }
    }

#pragma unroll
    for (int jd = 0; jd < 4; jd++)
#pragma unroll
        for (int r = 0; r < 4; r++) {
            float v = accO[jd][r] / l_run[r];
            v = v >= 0.f ? v : 0.01f * v;
            const int q = q0 + wave * 16 + lhi * 4 + r;
            const int d = jd * 16 + llo;
            attnL[((size_t)b * 2048 + q) * 1024 + hh * 64 + d] = f2bf(v);
        }
}

// ---------------- launcher ----------------
extern "C" void kernel_launch(void* const* d_in, const int* in_sizes, int n_in,
                              void* d_out, int out_size, void* d_ws, size_t ws_size,
                              hipStream_t stream) {
    const float* Z     = (const float*)d_in[0];
    const float* nmask = (const float*)d_in[1];
    const float* pmask = (const float*)d_in[2];
    const float* ln1_g = (const float*)d_in[3];
    const float* ln1_b = (const float*)d_in[4];
    const float* qkv_w = (const float*)d_in[5];
    const float* qkv_b = (const float*)d_in[6];
    const float* o_w   = (const float*)d_in[7];
    const float* ln2_g = (const float*)d_in[8];
    const float* ln2_b = (const float*)d_in[9];
    const float* p1_w  = (const float*)d_in[10];
    const float* p1_b  = (const float*)d_in[11];
    const float* p2_w  = (const float*)d_in[12];
    const float* p2_b  = (const float*)d_in[13];
    float* out = (float*)d_out;

    char* w = (char*)d_ws;
    auto take = [&](size_t bytes) -> char* {
        char* p = w;
        w += (bytes + 255) & ~(size_t)255;
        return p;
    };
    u16* qkvW  = (u16*)take((size_t)3072 * 1024 * 2);
    u16* oW    = (u16*)take((size_t)1024 * 1024 * 2);
    u16* p1W   = (u16*)take((size_t)4096 * 1024 * 2);
    u16* p2W   = (u16*)take((size_t)1024 * 4096 * 2);
    u16* Zn    = (u16*)take((size_t)4096 * 1024 * 2);  // reused for Zn2
    u16* Qb    = (u16*)take((size_t)32 * 2048 * 64 * 2);
    u16* Kb    = (u16*)take((size_t)32 * 2048 * 64 * 2);
    u16* Vt    = (u16*)take((size_t)32 * 64 * 2048 * 2);
    u16* attnL = (u16*)take((size_t)4096 * 1024 * 2);
    float* Z1  = (float*)take((size_t)4096 * 1024 * 4);
    u16* hbuf  = (u16*)take((size_t)4096 * 4096 * 2);

    // weight casts
    cast_bf16<<<dim3((3072 * 1024 / 4 + 255) / 256), 256, 0, stream>>>(qkv_w, qkvW, 3072 * 1024 / 4);
    cast_bf16<<<dim3((1024 * 1024 / 4 + 255) / 256), 256, 0, stream>>>(o_w, oW, 1024 * 1024 / 4);
    cast_bf16<<<dim3((4096 * 1024 / 4 + 255) / 256), 256, 0, stream>>>(p1_w, p1W, 4096 * 1024 / 4);
    cast_bf16<<<dim3((1024 * 4096 / 4 + 255) / 256), 256, 0, stream>>>(p2_w, p2W, 1024 * 4096 / 4);

    // LN1
    ln_bf16<<<dim3(4096), 256, 0, stream>>>(Z, ln1_g, ln1_b, Zn);
    // QKV projection, scatter to Q/K/Vt
    gemm_bt<0><<<dim3(24, 32), 256, 0, stream>>>(Zn, qkvW, qkv_b, nullptr, Vt, Qb, Kb, 4096, 3072, 1024);
    // attention
    attn_fused<<<dim3(32, 32), 256, 0, stream>>>(Qb, Kb, Vt, nmask, pmask, attnL);
    // o-projection + residual
    gemm_bt<1><<<dim3(8, 32), 256, 0, stream>>>(attnL, oW, nullptr, Z, Z1, nullptr, nullptr, 4096, 1024, 1024);
    // LN2
    ln_bf16<<<dim3(4096), 256, 0, stream>>>(Z1, ln2_g, ln2_b, Zn);
    // MLP up + relu
    gemm_bt<2><<<dim3(32, 32), 256, 0, stream>>>(Zn, p1W, p1_b, nullptr, hbuf, nullptr, nullptr, 4096, 4096, 1024);
    // MLP down + bias + residual -> out
    gemm_bt<3><<<dim3(8, 32), 256, 0, stream>>>(hbuf, p2W, p2_b, Z1, out, nullptr, nullptr, 4096, 1024, 4096);
}

// Round 2
// 476.270 us; speedup vs baseline: 1.2993x; 1.2993x over previous
//
#include <hip/hip_runtime.h>

typedef unsigned short u16;
typedef __attribute__((ext_vector_type(8))) short bf16x8;
typedef __attribute__((ext_vector_type(4))) float f32x4;

#define DEV static __device__ __forceinline__

DEV u16 f2bf(float f) {
    unsigned u = __float_as_uint(f);
    u += 0x7FFFu + ((u >> 16) & 1u);
    return (u16)(u >> 16);
}

typedef const __attribute__((address_space(1))) void* gas1_t;
typedef __attribute__((address_space(3))) void* gas3_t;

DEV void gl_lds16(const u16* g, u16* l) {
    __builtin_amdgcn_global_load_lds((gas1_t)g, (gas3_t)l, 16, 0, 0);
}

// swizzled LDS offset (u16 units) for 128B rows of 64 u16, 16B chunks
DEV int sw8(int row, int chunk) { return row * 64 + ((chunk ^ (row & 7)) << 3); }

// ---------------- elementwise f32 -> bf16 cast (weights) ----------------
__global__ void cast_bf16(const float* __restrict__ in, u16* __restrict__ out, int n4) {
    int i = blockIdx.x * blockDim.x + threadIdx.x;
    if (i < n4) {
        float4 v = ((const float4*)in)[i];
        ushort4 o;
        o.x = f2bf(v.x); o.y = f2bf(v.y); o.z = f2bf(v.z); o.w = f2bf(v.w);
        ((ushort4*)out)[i] = o;
    }
}

// qkv weight: cast + row permutation so out rows = [V(1024) | Q(1024) | K(1024)],
// each region ordered h*64+t.  src row = h*192 + region*64 + t.
__global__ void cast_qkv(const float* __restrict__ in, u16* __restrict__ out) {
    int i = blockIdx.x * 256 + threadIdx.x;   // 3072*256 float4s
    int orow = i >> 8, cc = i & 255;
    int region = orow >> 10, rem = orow & 1023, h = rem >> 6, t = rem & 63;
    int srow = h * 192 + region * 64 + t;
    float4 v = ((const float4*)in)[srow * 256 + cc];
    ushort4 o;
    o.x = f2bf(v.x); o.y = f2bf(v.y); o.z = f2bf(v.z); o.w = f2bf(v.w);
    ((ushort4*)out)[i] = o;
}

__global__ void permute_bias(const float* __restrict__ in, float* __restrict__ out) {
    int i = blockIdx.x * 256 + threadIdx.x;
    if (i < 3072) {
        int region = i >> 10, rem = i & 1023, h = rem >> 6, t = rem & 63;
        out[i] = in[h * 192 + region * 64 + t];
    }
}

// pack masks: u32 = (bf16(pmask) << 16) | bf16(nmask * log2(e))
__global__ void pack_mask(const float* __restrict__ nm, const float* __restrict__ pm,
                          unsigned* __restrict__ out, int n4) {
    int i = blockIdx.x * blockDim.x + threadIdx.x;
    if (i < n4) {
        float4 a = ((const float4*)nm)[i];
        float4 b = ((const float4*)pm)[i];
        uint4 o;
        o.x = ((unsigned)f2bf(b.x) << 16) | f2bf(a.x * 1.4426950f);
        o.y = ((unsigned)f2bf(b.y) << 16) | f2bf(a.y * 1.4426950f);
        o.z = ((unsigned)f2bf(b.z) << 16) | f2bf(a.z * 1.4426950f);
        o.w = ((unsigned)f2bf(b.w) << 16) | f2bf(a.w * 1.4426950f);
        ((uint4*)out)[i] = o;
    }
}

// ---------------- LayerNorm (D=1024) f32 -> bf16 ----------------
__global__ __launch_bounds__(256) void ln_bf16(const float* __restrict__ x,
                                               const float* __restrict__ gam,
                                               const float* __restrict__ bet,
                                               u16* __restrict__ y) {
    const int row = blockIdx.x;
    const int t = threadIdx.x;
    const float4 v = ((const float4*)(x + (size_t)row * 1024))[t];
    float s = v.x + v.y + v.z + v.w;
    float ss = v.x * v.x + v.y * v.y + v.z * v.z + v.w * v.w;
#pragma unroll
    for (int o = 1; o < 64; o <<= 1) {
        s += __shfl_xor(s, o);
        ss += __shfl_xor(ss, o);
    }
    __shared__ float rs[4], rss[4];
    const int wave = t >> 6, lane = t & 63;
    if (lane == 0) { rs[wave] = s; rss[wave] = ss; }
    __syncthreads();
    const float tot = rs[0] + rs[1] + rs[2] + rs[3];
    const float totss = rss[0] + rss[1] + rss[2] + rss[3];
    const float mu = tot * (1.0f / 1024.0f);
    const float var = totss * (1.0f / 1024.0f) - mu * mu;
    const float rstd = rsqrtf(var + 1e-5f);
    const float4 g4 = ((const float4*)gam)[t];
    const float4 b4 = ((const float4*)bet)[t];
    ushort4 o;
    o.x = f2bf((v.x - mu) * rstd * g4.x + b4.x);
    o.y = f2bf((v.y - mu) * rstd * g4.y + b4.y);
    o.z = f2bf((v.z - mu) * rstd * g4.z + b4.z);
    o.w = f2bf((v.w - mu) * rstd * g4.w + b4.w);
    ((ushort4*)(y + (size_t)row * 1024))[t] = o;
}

// ---------------- GEMM: C[M,N] = A[M,K] @ Bt[N,K]^T (+epilogue) ----------------
// EPI 0: +pbias; region=bx>>3: 0 -> f32 Vsc[row*1024+c], 1 -> Q bf16, 2 -> K bf16
// EPI 1: +res (f32), write f32 out0
// EPI 2: +bias, relu, write bf16 out0
// EPI 3: +bias +res, write f32 out0
template <int EPI>
__global__ __launch_bounds__(256, 2) void gemm_bt(const u16* __restrict__ A,
                                                  const u16* __restrict__ Bt,
                                                  const float* __restrict__ bias,
                                                  const float* __restrict__ res,
                                                  void* __restrict__ out0,
                                                  void* __restrict__ out1,
                                                  void* __restrict__ out2,
                                                  int M, int N, int K) {
    __shared__ __align__(16) u16 As[128 * 32];
    __shared__ __align__(16) u16 Bs[128 * 32];
    const int tid = threadIdx.x;
    const int wave = tid >> 6, lane = tid & 63;
    const int lhi = lane >> 4, llo = lane & 15;
    const int bx = blockIdx.x, by = blockIdx.y;

    const int arow = wave * 32 + (lane >> 2);
    const int acol = (lane & 3) * 8;
    const u16* gA = A + (size_t)(by * 128 + arow) * K + acol;
    const u16* gB = Bt + (size_t)(bx * 128 + arow) * K + acol;
    u16* lA = As + wave * 1024 + lane * 8;
    u16* lB = Bs + wave * 1024 + lane * 8;

    const int wr = wave >> 1, wc = wave & 1;
    const f32x4 zero = {0.f, 0.f, 0.f, 0.f};
    f32x4 acc[4][4];
#pragma unroll
    for (int i = 0; i < 4; i++)
#pragma unroll
        for (int j = 0; j < 4; j++) acc[i][j] = zero;

    for (int k0 = 0; k0 < K; k0 += 32) {
        __syncthreads();
        gl_lds16(gA, lA);
        gl_lds16(gA + 16 * (size_t)K, lA + 512);
        gl_lds16(gB, lB);
        gl_lds16(gB + 16 * (size_t)K, lB + 512);
        gA += 32; gB += 32;
        __syncthreads();
        bf16x8 af[4], bfr[4];
#pragma unroll
        for (int i = 0; i < 4; i++)
            af[i] = *(const bf16x8*)(As + (wr * 64 + i * 16 + llo) * 32 + lhi * 8);
#pragma unroll
        for (int j = 0; j < 4; j++)
            bfr[j] = *(const bf16x8*)(Bs + (wc * 64 + j * 16 + llo) * 32 + lhi * 8);
#pragma unroll
        for (int i = 0; i < 4; i++)
#pragma unroll
            for (int j = 0; j < 4; j++)
                acc[i][j] = __builtin_amdgcn_mfma_f32_16x16x32_bf16(af[i], bfr[j], acc[i][j], 0, 0, 0);
    }

    const int rbase = by * 128 + wr * 64 + lhi * 4;
    const int cbase = bx * 128 + wc * 64 + llo;
#pragma unroll
    for (int i = 0; i < 4; i++) {
#pragma unroll
        for (int j = 0; j < 4; j++) {
#pragma unroll
            for (int r = 0; r < 4; r++) {
                const int row = rbase + i * 16 + r;
                const int col = cbase + j * 16;
                float v = acc[i][j][r];
                if (EPI == 0) {
                    v += bias[col];
                    const int region = col >> 10;   // uniform per block
                    const int c = col & 1023;       // h*64 + t
                    const int b = row >> 11, n = row & 2047;
                    if (region == 0) {
                        ((float*)out0)[(size_t)row * 1024 + c] = v;  // Vsc f32
                    } else {
                        const int h = c >> 6, t = c & 63;
                        u16* dst = (region == 1) ? (u16*)out1 : (u16*)out2;
                        dst[(((size_t)(b * 16 + h)) * 2048 + n) * 64 + t] = f2bf(v);
                    }
                } else if (EPI == 1) {
                    ((float*)out0)[(size_t)row * N + col] = v + res[(size_t)row * N + col];
                } else if (EPI == 2) {
                    v += bias[col];
                    v = v > 0.f ? v : 0.f;
                    ((u16*)out0)[(size_t)row * N + col] = f2bf(v);
                } else {
                    v += bias[col] + res[(size_t)row * N + col];
                    ((float*)out0)[(size_t)row * N + col] = v;
                }
            }
        }
    }
}

// ---------------- V transpose: Vsc f32 [B*N][1024] -> Vt bf16 [BH][64][2048] --
__global__ __launch_bounds__(256) void vtrans(const float* __restrict__ Vsc,
                                              u16* __restrict__ Vt) {
    __shared__ u16 Ts[64 * 72];
    const int nt = blockIdx.x;  // n-tile (0..31)
    const int bh = blockIdx.y;  // 0..31
    const int b = bh >> 4, h = bh & 15;
    const int t = threadIdx.x;
    const int n0 = nt * 64;
    const int nr = t >> 2;
    const int dq = (t & 3) * 16;
    const float* src = Vsc + ((size_t)(b * 2048 + n0 + nr)) * 1024 + h * 64 + dq;
    float4 v0 = ((const float4*)src)[0];
    float4 v1 = ((const float4*)src)[1];
    float4 v2 = ((const float4*)src)[2];
    float4 v3 = ((const float4*)src)[3];
    u16* c0 = Ts + nr;
    c0[(dq + 0) * 72]  = f2bf(v0.x); c0[(dq + 1) * 72]  = f2bf(v0.y);
    c0[(dq + 2) * 72]  = f2bf(v0.z); c0[(dq + 3) * 72]  = f2bf(v0.w);
    c0[(dq + 4) * 72]  = f2bf(v1.x); c0[(dq + 5) * 72]  = f2bf(v1.y);
    c0[(dq + 6) * 72]  = f2bf(v1.z); c0[(dq + 7) * 72]  = f2bf(v1.w);
    c0[(dq + 8) * 72]  = f2bf(v2.x); c0[(dq + 9) * 72]  = f2bf(v2.y);
    c0[(dq + 10) * 72] = f2bf(v2.z); c0[(dq + 11) * 72] = f2bf(v2.w);
    c0[(dq + 12) * 72] = f2bf(v3.x); c0[(dq + 13) * 72] = f2bf(v3.y);
    c0[(dq + 14) * 72] = f2bf(v3.z); c0[(dq + 15) * 72] = f2bf(v3.w);
    __syncthreads();
    const int d = t >> 2, n8 = (t & 3) * 16;
    bf16x8 o0 = *(const bf16x8*)(Ts + d * 72 + n8);
    bf16x8 o1 = *(const bf16x8*)(Ts + d * 72 + n8 + 8);
    u16* dst = Vt + ((size_t)bh * 64 + d) * 2048 + n0 + n8;
    *(bf16x8*)dst = o0;
    *(bf16x8*)(dst + 8) = o1;
}

// ---------------- fused flash-style attention v2 ----------------
// grid: 512 blocks, id = hh*32 + (b*16 + qt)  (mask-sharing blocks on same XCD)
// q-tile 128 (wave owns 32 rows), m-tile 64. One-pass softmax (no running max).
__global__ __launch_bounds__(256, 2) void attn_fused2(const u16* __restrict__ Qg,
                                                      const u16* __restrict__ Kg,
                                                      const u16* __restrict__ Vt,
                                                      const unsigned* __restrict__ Mp,
                                                      u16* __restrict__ attnL) {
    __shared__ __align__(16) u16 Qs[128 * 64];
    __shared__ __align__(16) u16 Ks[64 * 64];
    __shared__ __align__(16) u16 Vs[64 * 64];  // [d][m]
    __shared__ __align__(16) u16 Ps[128 * 64];
    const int tid = threadIdx.x, wave = tid >> 6, lane = tid & 63;
    const int lhi = lane >> 4, llo = lane & 15;
    const int id = blockIdx.x;
    const int hh = id >> 5, bq = id & 31;
    const int b = bq >> 4, qt = bq & 15;
    const int bh = b * 16 + hh;
    const int q0 = qt * 128;
    const int l3 = lane >> 3, l7 = lane & 7;
    const int swcol = (l7 ^ (l3 & 7)) * 8;   // swizzled source column (u16)

    // stage Q tile (128 rows) once
#pragma unroll
    for (int s = 0; s < 4; s++) {
        const int row = wave * 32 + s * 8 + l3;
        gl_lds16(Qg + ((size_t)bh * 2048 + q0 + row) * 64 + swcol,
                 Qs + wave * 2048 + s * 512 + lane * 8);
    }

    const unsigned* Mpb = Mp + (size_t)b * 2048 * 2048;
    int midx[2][4];
#pragma unroll
    for (int i = 0; i < 2; i++)
#pragma unroll
        for (int r = 0; r < 4; r++)
            midx[i][r] = (q0 + wave * 32 + i * 16 + lhi * 4 + r) * 2048 + llo;

    const f32x4 zero = {0.f, 0.f, 0.f, 0.f};
    f32x4 accO[2][4];
    float lsum[2][4];
#pragma unroll
    for (int i = 0; i < 2; i++)
#pragma unroll
        for (int j = 0; j < 4; j++) accO[i][j] = zero;
#pragma unroll
    for (int i = 0; i < 2; i++)
#pragma unroll
        for (int r = 0; r < 4; r++) lsum[i][r] = 0.f;

    const float CS = 0.125f * 1.4426950f;  // fold /sqrt(64) and log2(e)

    for (int m0 = 0; m0 < 2048; m0 += 64) {
        __syncthreads();
        // stage K[m0..m0+64) and Vt[:, m0..m0+64) (swizzled)
#pragma unroll
        for (int s = 0; s < 2; s++) {
            const int row = wave * 16 + s * 8 + l3;
            gl_lds16(Kg + ((size_t)bh * 2048 + m0 + row) * 64 + swcol,
                     Ks + wave * 1024 + s * 512 + lane * 8);
            gl_lds16(Vt + ((size_t)bh * 64 + row) * 2048 + m0 + swcol,
                     Vs + wave * 1024 + s * 512 + lane * 8);
        }
        // packed mask loads ride the same latency window as the staging
        unsigned mv[2][4][4];
#pragma unroll
        for (int i = 0; i < 2; i++)
#pragma unroll
            for (int r = 0; r < 4; r++)
#pragma unroll
                for (int j = 0; j < 4; j++)
                    mv[i][r][j] = Mpb[midx[i][r] + m0 + j * 16];
        __syncthreads();

        // S = Q K^T (raw, scale folded into exp2 arg)
        f32x4 sacc[2][4];
#pragma unroll
        for (int i = 0; i < 2; i++)
#pragma unroll
            for (int j = 0; j < 4; j++) sacc[i][j] = zero;
#pragma unroll
        for (int kk = 0; kk < 2; kk++) {
            bf16x8 aq[2];
#pragma unroll
            for (int i = 0; i < 2; i++)
                aq[i] = *(const bf16x8*)(Qs + sw8(wave * 32 + i * 16 + llo, kk * 4 + lhi));
#pragma unroll
            for (int j = 0; j < 4; j++) {
                const bf16x8 bk = *(const bf16x8*)(Ks + sw8(j * 16 + llo, kk * 4 + lhi));
                sacc[0][j] = __builtin_amdgcn_mfma_f32_16x16x32_bf16(aq[0], bk, sacc[0][j], 0, 0, 0);
                sacc[1][j] = __builtin_amdgcn_mfma_f32_16x16x32_bf16(aq[1], bk, sacc[1][j], 0, 0, 0);
            }
        }

        // P = exp(S/8 + nmask) * pmask ; l += exp (unmasked denominator)
#pragma unroll
        for (int i = 0; i < 2; i++)
#pragma unroll
            for (int j = 0; j < 4; j++)
#pragma unroll
                for (int r = 0; r < 4; r++) {
                    const unsigned u = mv[i][r][j];
                    const float nm = __uint_as_float(u << 16);
                    const float pm = __uint_as_float(u & 0xFFFF0000u);
                    const float e = exp2f(fmaf(sacc[i][j][r], CS, nm));
                    lsum[i][r] += e;
                    const float p = e * pm;
                    const u16 pb = (u16)((__float_as_uint(p) + 0x8000u) >> 16);
                    const int q_rel = wave * 32 + i * 16 + lhi * 4 + r;
                    const int ch = (j * 2 + (llo >> 3)) ^ (q_rel & 7);
                    Ps[q_rel * 64 + ch * 8 + (llo & 7)] = pb;
                }

        // O += P @ V  (Ps rows wave-private)
#pragma unroll
        for (int kk = 0; kk < 2; kk++) {
            bf16x8 ap[2];
#pragma unroll
            for (int i = 0; i < 2; i++)
                ap[i] = *(const bf16x8*)(Ps + sw8(wave * 32 + i * 16 + llo, kk * 4 + lhi));
#pragma unroll
            for (int jd = 0; jd < 4; jd++) {
                const bf16x8 bv = *(const bf16x8*)(Vs + sw8(jd * 16 + llo, kk * 4 + lhi));
                accO[0][jd] = __builtin_amdgcn_mfma_f32_16x16x32_bf16(ap[0], bv, accO[0][jd], 0, 0, 0);
                accO[1][jd] = __builtin_amdgcn_mfma_f32_16x16x32_bf16(ap[1], bv, accO[1][jd], 0, 0, 0);
            }
        }
    }

    // reduce l over the 16 columns, epilogue leaky_relu(O/l)
#pragma unroll
    for (int i = 0; i < 2; i++)
#pragma unroll
        for (int r = 0; r < 4; r++) {
#pragma unroll
            for (int o = 1; o < 16; o <<= 1) lsum[i][r] += __shfl_xor(lsum[i][r], o);
            lsum[i][r] = 1.0f / lsum[i][r];
        }
#pragma unroll
    for (int i = 0; i < 2; i++)
#pragma unroll
        for (int jd = 0; jd < 4; jd++)
#pragma unroll
            for (int r = 0; r < 4; r++) {
                float v = accO[i][jd][r] * lsum[i][r];
                v = v >= 0.f ? v : 0.01f * v;
                const int q = q0 + wave * 32 + i * 16 + lhi * 4 + r;
                attnL[((size_t)b * 2048 + q) * 1024 + hh * 64 + jd * 16 + llo] = f2bf(v);
            }
}

// ---------------- launcher ----------------
extern "C" void kernel_launch(void* const* d_in, const int* in_sizes, int n_in,
                              void* d_out, int out_size, void* d_ws, size_t ws_size,
                              hipStream_t stream) {
    const float* Z     = (const float*)d_in[0];
    const float* nmask = (const float*)d_in[1];
    const float* pmask = (const float*)d_in[2];
    const float* ln1_g = (const float*)d_in[3];
    const float* ln1_b = (const float*)d_in[4];
    const float* qkv_w = (const float*)d_in[5];
    const float* qkv_b = (const float*)d_in[6];
    const float* o_w   = (const float*)d_in[7];
    const float* ln2_g = (const float*)d_in[8];
    const float* ln2_b = (const float*)d_in[9];
    const float* p1_w  = (const float*)d_in[10];
    const float* p1_b  = (const float*)d_in[11];
    const float* p2_w  = (const float*)d_in[12];
    const float* p2_b  = (const float*)d_in[13];
    float* out = (float*)d_out;

    char* w = (char*)d_ws;
    auto take = [&](size_t bytes) -> char* {
        char* p = w;
        w += (bytes + 255) & ~(size_t)255;
        return p;
    };
    u16* qkvW   = (u16*)take((size_t)3072 * 1024 * 2);
    u16* oW     = (u16*)take((size_t)1024 * 1024 * 2);
    u16* p1W    = (u16*)take((size_t)4096 * 1024 * 2);
    u16* p2W    = (u16*)take((size_t)1024 * 4096 * 2);
    u16* Zn     = (u16*)take((size_t)4096 * 1024 * 2);   // reused for Zn2
    u16* Qb     = (u16*)take((size_t)32 * 2048 * 64 * 2);
    u16* Kb     = (u16*)take((size_t)32 * 2048 * 64 * 2);
    u16* Vt     = (u16*)take((size_t)32 * 64 * 2048 * 2);
    u16* attnL  = (u16*)take((size_t)4096 * 1024 * 2);
    float* Z1   = (float*)take((size_t)4096 * 1024 * 4);
    u16* hbuf   = (u16*)take((size_t)4096 * 4096 * 2);
    unsigned* Mp = (unsigned*)take((size_t)2 * 2048 * 2048 * 4);
    float* pbias = (float*)take((size_t)3072 * 4);
    float* Vsc   = (float*)hbuf;  // alias: Vsc dead before hbuf is written

    // weight prep
    cast_qkv<<<dim3(3072), 256, 0, stream>>>(qkv_w, qkvW);
    permute_bias<<<dim3(12), 256, 0, stream>>>(qkv_b, pbias);
    cast_bf16<<<dim3(1024), 256, 0, stream>>>(o_w, oW, 1024 * 1024 / 4);
    cast_bf16<<<dim3(4096), 256, 0, stream>>>(p1_w, p1W, 4096 * 1024 / 4);
    cast_bf16<<<dim3(4096), 256, 0, stream>>>(p2_w, p2W, 1024 * 4096 / 4);
    pack_mask<<<dim3(8192), 256, 0, stream>>>(nmask, pmask, Mp, 2 * 2048 * 2048 / 4);

    // LN1
    ln_bf16<<<dim3(4096), 256, 0, stream>>>(Z, ln1_g, ln1_b, Zn);
    // QKV projection: V -> f32 scratch, Q/K -> bf16 [BH][N][64]
    gemm_bt<0><<<dim3(24, 32), 256, 0, stream>>>(Zn, qkvW, pbias, nullptr, Vsc, Qb, Kb, 4096, 3072, 1024);
    // V transpose -> Vt [BH][64][2048]
    vtrans<<<dim3(32, 32), 256, 0, stream>>>(Vsc, Vt);
    // attention
    attn_fused2<<<dim3(512), 256, 0, stream>>>(Qb, Kb, Vt, Mp, attnL);
    // o-projection + residual
    gemm_bt<1><<<dim3(8, 32), 256, 0, stream>>>(attnL, oW, nullptr, Z, Z1, nullptr, nullptr, 4096, 1024, 1024);
    // LN2
    ln_bf16<<<dim3(4096), 256, 0, stream>>>(Z1, ln2_g, ln2_b, Zn);
    // MLP up + relu
    gemm_bt<2><<<dim3(32, 32), 256, 0, stream>>>(Zn, p1W, p1_b, nullptr, hbuf, nullptr, nullptr, 4096, 4096, 1024);
    // MLP down + bias + residual -> out
    gemm_bt<3><<<dim3(8, 32), 256, 0, stream>>>(hbuf, p2W, p2_b, Z1, out, nullptr, nullptr, 4096, 1024, 4096);
}

// Round 3
// 475.187 us; speedup vs baseline: 1.3023x; 1.0023x over previous
//
#include <hip/hip_runtime.h>

typedef unsigned short u16;
typedef __attribute__((ext_vector_type(8))) short bf16x8;
typedef __attribute__((ext_vector_type(4))) float f32x4;

#define DEV static __device__ __forceinline__

DEV u16 f2bf(float f) {
    unsigned u = __float_as_uint(f);
    u += 0x7FFFu + ((u >> 16) & 1u);
    return (u16)(u >> 16);
}

typedef const __attribute__((address_space(1))) void* gas1_t;
typedef __attribute__((address_space(3))) void* gas3_t;

DEV void gl_lds16(const u16* g, u16* l) {
    __builtin_amdgcn_global_load_lds((gas1_t)g, (gas3_t)l, 16, 0, 0);
}

// swizzled LDS offset (u16 units) for 128B rows of 64 u16, 16B chunks
DEV int sw8(int row, int chunk) { return row * 64 + ((chunk ^ (row & 7)) << 3); }

// ---------------- elementwise f32 -> bf16 cast (weights) ----------------
__global__ void cast_bf16(const float* __restrict__ in, u16* __restrict__ out, int n4) {
    int i = blockIdx.x * blockDim.x + threadIdx.x;
    if (i < n4) {
        float4 v = ((const float4*)in)[i];
        ushort4 o;
        o.x = f2bf(v.x); o.y = f2bf(v.y); o.z = f2bf(v.z); o.w = f2bf(v.w);
        ((ushort4*)out)[i] = o;
    }
}

// qkv weight: cast + row permutation so out rows = [V(1024) | Q(1024) | K(1024)]
__global__ void cast_qkv(const float* __restrict__ in, u16* __restrict__ out) {
    int i = blockIdx.x * 256 + threadIdx.x;   // 3072*256 float4s
    int orow = i >> 8, cc = i & 255;
    int region = orow >> 10, rem = orow & 1023, h = rem >> 6, t = rem & 63;
    int srow = h * 192 + region * 64 + t;
    float4 v = ((const float4*)in)[srow * 256 + cc];
    ushort4 o;
    o.x = f2bf(v.x); o.y = f2bf(v.y); o.z = f2bf(v.z); o.w = f2bf(v.w);
    ((ushort4*)out)[i] = o;
}

__global__ void permute_bias(const float* __restrict__ in, float* __restrict__ out) {
    int i = blockIdx.x * 256 + threadIdx.x;
    if (i < 3072) {
        int region = i >> 10, rem = i & 1023, h = rem >> 6, t = rem & 63;
        out[i] = in[h * 192 + region * 64 + t];
    }
}

// pack masks: u32 = (bf16(pmask) << 16) | bf16(nmask * log2(e))
__global__ void pack_mask(const float* __restrict__ nm, const float* __restrict__ pm,
                          unsigned* __restrict__ out, int n4) {
    int i = blockIdx.x * blockDim.x + threadIdx.x;
    if (i < n4) {
        float4 a = ((const float4*)nm)[i];
        float4 b = ((const float4*)pm)[i];
        uint4 o;
        o.x = ((unsigned)f2bf(b.x) << 16) | f2bf(a.x * 1.4426950f);
        o.y = ((unsigned)f2bf(b.y) << 16) | f2bf(a.y * 1.4426950f);
        o.z = ((unsigned)f2bf(b.z) << 16) | f2bf(a.z * 1.4426950f);
        o.w = ((unsigned)f2bf(b.w) << 16) | f2bf(a.w * 1.4426950f);
        ((uint4*)out)[i] = o;
    }
}

// ---------------- LayerNorm (D=1024) f32 -> bf16 ----------------
__global__ __launch_bounds__(256) void ln_bf16(const float* __restrict__ x,
                                               const float* __restrict__ gam,
                                               const float* __restrict__ bet,
                                               u16* __restrict__ y) {
    const int row = blockIdx.x;
    const int t = threadIdx.x;
    const float4 v = ((const float4*)(x + (size_t)row * 1024))[t];
    float s = v.x + v.y + v.z + v.w;
    float ss = v.x * v.x + v.y * v.y + v.z * v.z + v.w * v.w;
#pragma unroll
    for (int o = 1; o < 64; o <<= 1) {
        s += __shfl_xor(s, o);
        ss += __shfl_xor(ss, o);
    }
    __shared__ float rs[4], rss[4];
    const int wave = t >> 6, lane = t & 63;
    if (lane == 0) { rs[wave] = s; rss[wave] = ss; }
    __syncthreads();
    const float tot = rs[0] + rs[1] + rs[2] + rs[3];
    const float totss = rss[0] + rss[1] + rss[2] + rss[3];
    const float mu = tot * (1.0f / 1024.0f);
    const float var = totss * (1.0f / 1024.0f) - mu * mu;
    const float rstd = rsqrtf(var + 1e-5f);
    const float4 g4 = ((const float4*)gam)[t];
    const float4 b4 = ((const float4*)bet)[t];
    ushort4 o;
    o.x = f2bf((v.x - mu) * rstd * g4.x + b4.x);
    o.y = f2bf((v.y - mu) * rstd * g4.y + b4.y);
    o.z = f2bf((v.z - mu) * rstd * g4.z + b4.z);
    o.w = f2bf((v.w - mu) * rstd * g4.w + b4.w);
    ((ushort4*)(y + (size_t)row * 1024))[t] = o;
}

// ---------------- GEMM: C[M,N] = A[M,K] @ Bt[N,K]^T (+epilogue) ----------------
// BN = 128 (waves 2x2, acc 4x4) or 64 (waves 4x1, acc 2x4).
// EPI 0: +pbias; region: 0 -> f32 Vsc, 1 -> Q bf16, 2 -> K bf16 (BN=128 only)
// EPI 1: +res (f32), write f32 out0
// EPI 2: +bias, relu, write bf16 out0
// EPI 3: +bias +res, write f32 out0
template <int EPI, int BN>
__global__ __launch_bounds__(256, 2) void gemm_bt(const u16* __restrict__ A,
                                                  const u16* __restrict__ Bt,
                                                  const float* __restrict__ bias,
                                                  const float* __restrict__ res,
                                                  void* __restrict__ out0,
                                                  void* __restrict__ out1,
                                                  void* __restrict__ out2,
                                                  int M, int N, int K) {
    constexpr int RT = (BN == 128) ? 4 : 2;   // 16-row tiles per wave
    __shared__ __align__(16) u16 As[128 * 32];
    __shared__ __align__(16) u16 Bs[BN * 32];
    const int tid = threadIdx.x;
    const int wave = tid >> 6, lane = tid & 63;
    const int lhi = lane >> 4, llo = lane & 15;
    const int bx = blockIdx.x, by = blockIdx.y;
    const int wr = (BN == 128) ? (wave >> 1) : wave;
    const int wc = (BN == 128) ? (wave & 1) : 0;

    const int arow = wave * 32 + (lane >> 2);
    const int acol = (lane & 3) * 8;
    const u16* gA = A + (size_t)(by * 128 + arow) * K + acol;
    u16* lA = As + wave * 1024 + lane * 8;
    const int brow = (BN == 128) ? arow : (wave * 16 + (lane >> 2));
    const u16* gB = Bt + (size_t)(bx * BN + brow) * K + acol;
    u16* lB = Bs + ((BN == 128) ? wave * 1024 : wave * 512) + lane * 8;

    const f32x4 zero = {0.f, 0.f, 0.f, 0.f};
    f32x4 acc[RT][4];
#pragma unroll
    for (int i = 0; i < RT; i++)
#pragma unroll
        for (int j = 0; j < 4; j++) acc[i][j] = zero;

    for (int k0 = 0; k0 < K; k0 += 32) {
        __syncthreads();
        gl_lds16(gA, lA);
        gl_lds16(gA + 16 * (size_t)K, lA + 512);
        gl_lds16(gB, lB);
        if (BN == 128) gl_lds16(gB + 16 * (size_t)K, lB + 512);
        gA += 32; gB += 32;
        __syncthreads();
        bf16x8 af[RT], bfr[4];
#pragma unroll
        for (int i = 0; i < RT; i++)
            af[i] = *(const bf16x8*)(As + (wr * (RT * 16) + i * 16 + llo) * 32 + lhi * 8);
#pragma unroll
        for (int j = 0; j < 4; j++)
            bfr[j] = *(const bf16x8*)(Bs + (wc * 64 + j * 16 + llo) * 32 + lhi * 8);
#pragma unroll
        for (int i = 0; i < RT; i++)
#pragma unroll
            for (int j = 0; j < 4; j++)
                acc[i][j] = __builtin_amdgcn_mfma_f32_16x16x32_bf16(af[i], bfr[j], acc[i][j], 0, 0, 0);
    }

    const int rbase = by * 128 + wr * (RT * 16) + lhi * 4;
    const int cbase = bx * BN + wc * 64 + llo;
#pragma unroll
    for (int i = 0; i < RT; i++) {
#pragma unroll
        for (int j = 0; j < 4; j++) {
#pragma unroll
            for (int r = 0; r < 4; r++) {
                const int row = rbase + i * 16 + r;
                const int col = cbase + j * 16;
                float v = acc[i][j][r];
                if constexpr (EPI == 0) {
                    v += bias[col];
                    const int region = col >> 10;   // uniform per block
                    const int c = col & 1023;       // h*64 + t
                    const int b = row >> 11, n = row & 2047;
                    if (region == 0) {
                        ((float*)out0)[(size_t)row * 1024 + c] = v;  // Vsc f32
                    } else {
                        const int h = c >> 6, t = c & 63;
                        u16* dst = (region == 1) ? (u16*)out1 : (u16*)out2;
                        dst[(((size_t)(b * 16 + h)) * 2048 + n) * 64 + t] = f2bf(v);
                    }
                } else if constexpr (EPI == 1) {
                    ((float*)out0)[(size_t)row * N + col] = v + res[(size_t)row * N + col];
                } else if constexpr (EPI == 2) {
                    v += bias[col];
                    v = v > 0.f ? v : 0.f;
                    ((u16*)out0)[(size_t)row * N + col] = f2bf(v);
                } else {
                    v += bias[col] + res[(size_t)row * N + col];
                    ((float*)out0)[(size_t)row * N + col] = v;
                }
            }
        }
    }
}

// ---------------- V transpose: Vsc f32 [B*N][1024] -> Vt bf16 [BH][64][2048] --
__global__ __launch_bounds__(256) void vtrans(const float* __restrict__ Vsc,
                                              u16* __restrict__ Vt) {
    __shared__ u16 Ts[64 * 72];
    const int nt = blockIdx.x;  // n-tile (0..31)
    const int bh = blockIdx.y;  // 0..31
    const int b = bh >> 4, h = bh & 15;
    const int t = threadIdx.x;
    const int n0 = nt * 64;
    const int nr = t >> 2;
    const int dq = (t & 3) * 16;
    const float* src = Vsc + ((size_t)(b * 2048 + n0 + nr)) * 1024 + h * 64 + dq;
    float4 v0 = ((const float4*)src)[0];
    float4 v1 = ((const float4*)src)[1];
    float4 v2 = ((const float4*)src)[2];
    float4 v3 = ((const float4*)src)[3];
    u16* c0 = Ts + nr;
    c0[(dq + 0) * 72]  = f2bf(v0.x); c0[(dq + 1) * 72]  = f2bf(v0.y);
    c0[(dq + 2) * 72]  = f2bf(v0.z); c0[(dq + 3) * 72]  = f2bf(v0.w);
    c0[(dq + 4) * 72]  = f2bf(v1.x); c0[(dq + 5) * 72]  = f2bf(v1.y);
    c0[(dq + 6) * 72]  = f2bf(v1.z); c0[(dq + 7) * 72]  = f2bf(v1.w);
    c0[(dq + 8) * 72]  = f2bf(v2.x); c0[(dq + 9) * 72]  = f2bf(v2.y);
    c0[(dq + 10) * 72] = f2bf(v2.z); c0[(dq + 11) * 72] = f2bf(v2.w);
    c0[(dq + 12) * 72] = f2bf(v3.x); c0[(dq + 13) * 72] = f2bf(v3.y);
    c0[(dq + 14) * 72] = f2bf(v3.z); c0[(dq + 15) * 72] = f2bf(v3.w);
    __syncthreads();
    const int d = t >> 2, n8 = (t & 3) * 16;
    bf16x8 o0 = *(const bf16x8*)(Ts + d * 72 + n8);
    bf16x8 o1 = *(const bf16x8*)(Ts + d * 72 + n8 + 8);
    u16* dst = Vt + ((size_t)bh * 64 + d) * 2048 + n0 + n8;
    *(bf16x8*)dst = o0;
    *(bf16x8*)(dst + 8) = o1;
}

// ---------------- fused flash-style attention v3 ----------------
// grid 512, id = hh*32 + (b*16 + qt). q-tile 128 (wave owns 32 rows), m-tile 64.
// One-pass softmax; double-buffered register prefetch of packed masks;
// Ps padded stride-72 (immediate-offset ds_write_b16, no per-element addr VALU).
__global__ __launch_bounds__(256, 2) void attn_fused3(const u16* __restrict__ Qg,
                                                      const u16* __restrict__ Kg,
                                                      const u16* __restrict__ Vt,
                                                      const unsigned* __restrict__ Mp,
                                                      u16* __restrict__ attnL) {
    __shared__ __align__(16) u16 Qs[128 * 64];
    __shared__ __align__(16) u16 Ks[64 * 64];
    __shared__ __align__(16) u16 Vs[64 * 64];   // [d][m]
    __shared__ __align__(16) u16 Ps[128 * 72];  // padded rows (144 B, 16B-aligned)
    const int tid = threadIdx.x, wave = tid >> 6, lane = tid & 63;
    const int lhi = lane >> 4, llo = lane & 15;
    const int id = blockIdx.x;
    const int hh = id >> 5, bq = id & 31;
    const int b = bq >> 4, qt = bq & 15;
    const int bh = b * 16 + hh;
    const int q0 = qt * 128;
    const int l3 = lane >> 3, l7 = lane & 7;
    const int swcol = (l7 ^ (l3 & 7)) * 8;   // swizzled source column (u16)

    // stage Q tile (128 rows) once
#pragma unroll
    for (int s = 0; s < 4; s++) {
        const int row = wave * 32 + s * 8 + l3;
        gl_lds16(Qg + ((size_t)bh * 2048 + q0 + row) * 64 + swcol,
                 Qs + wave * 2048 + s * 512 + lane * 8);
    }

    const unsigned* Mpb = Mp + (size_t)b * 2048 * 2048;
    int midx[2][4];
#pragma unroll
    for (int i = 0; i < 2; i++)
#pragma unroll
        for (int r = 0; r < 4; r++)
            midx[i][r] = (q0 + wave * 32 + i * 16 + lhi * 4 + r) * 2048 + llo;

    const f32x4 zero = {0.f, 0.f, 0.f, 0.f};
    f32x4 accO[2][4];
    float lsum[2][4];
#pragma unroll
    for (int i = 0; i < 2; i++)
#pragma unroll
        for (int j = 0; j < 4; j++) accO[i][j] = zero;
#pragma unroll
    for (int i = 0; i < 2; i++)
#pragma unroll
        for (int r = 0; r < 4; r++) lsum[i][r] = 0.f;

    const float CS = 0.125f * 1.4426950f;

    unsigned mvA[2][4][4], mvB[2][4][4];
    // initial prefetch for m0 = 0
#pragma unroll
    for (int i = 0; i < 2; i++)
#pragma unroll
        for (int r = 0; r < 4; r++)
#pragma unroll
            for (int j = 0; j < 4; j++) mvA[i][r][j] = Mpb[midx[i][r] + j * 16];

    auto body = [&](int m0, unsigned (&cur)[2][4][4], unsigned (&nxt)[2][4][4]) {
        __syncthreads();
        // stage K[m0..m0+64) and Vt[:, m0..m0+64) (swizzled)
#pragma unroll
        for (int s = 0; s < 2; s++) {
            const int row = wave * 16 + s * 8 + l3;
            gl_lds16(Kg + ((size_t)bh * 2048 + m0 + row) * 64 + swcol,
                     Ks + wave * 1024 + s * 512 + lane * 8);
            gl_lds16(Vt + ((size_t)bh * 64 + row) * 2048 + m0 + swcol,
                     Vs + wave * 1024 + s * 512 + lane * 8);
        }
        __syncthreads();

        // prefetch next tile's masks NOW; consumed one full iteration later
        const int mn = (m0 + 64) & 2047;
#pragma unroll
        for (int i = 0; i < 2; i++)
#pragma unroll
            for (int r = 0; r < 4; r++)
#pragma unroll
                for (int j = 0; j < 4; j++) nxt[i][r][j] = Mpb[midx[i][r] + mn + j * 16];

        // S = Q K^T
        f32x4 sacc[2][4];
#pragma unroll
        for (int i = 0; i < 2; i++)
#pragma unroll
            for (int j = 0; j < 4; j++) sacc[i][j] = zero;
#pragma unroll
        for (int kk = 0; kk < 2; kk++) {
            bf16x8 aq[2];
#pragma unroll
            for (int i = 0; i < 2; i++)
                aq[i] = *(const bf16x8*)(Qs + sw8(wave * 32 + i * 16 + llo, kk * 4 + lhi));
#pragma unroll
            for (int j = 0; j < 4; j++) {
                const bf16x8 bk = *(const bf16x8*)(Ks + sw8(j * 16 + llo, kk * 4 + lhi));
                sacc[0][j] = __builtin_amdgcn_mfma_f32_16x16x32_bf16(aq[0], bk, sacc[0][j], 0, 0, 0);
                sacc[1][j] = __builtin_amdgcn_mfma_f32_16x16x32_bf16(aq[1], bk, sacc[1][j], 0, 0, 0);
            }
        }

        // P = exp2(S*CS + nm) * pm ; l += exp (unmasked denominator)
#pragma unroll
        for (int i = 0; i < 2; i++) {
            const int pb0 = (wave * 32 + i * 16 + lhi * 4) * 72 + llo;  // + r*72 + j*16 imm
#pragma unroll
            for (int j = 0; j < 4; j++)
#pragma unroll
                for (int r = 0; r < 4; r++) {
                    const unsigned u = cur[i][r][j];
                    const float nm = __uint_as_float(u << 16);
                    const float pm = __uint_as_float(u & 0xFFFF0000u);
                    const float e = exp2f(fmaf(sacc[i][j][r], CS, nm));
                    lsum[i][r] += e;
                    const float p = e * pm;
                    Ps[pb0 + r * 72 + j * 16] = (u16)((__float_as_uint(p) + 0x8000u) >> 16);
                }
        }

        // O += P @ V  (Ps rows wave-private)
#pragma unroll
        for (int kk = 0; kk < 2; kk++) {
            bf16x8 ap[2];
#pragma unroll
            for (int i = 0; i < 2; i++)
                ap[i] = *(const bf16x8*)(Ps + (wave * 32 + i * 16 + llo) * 72 + kk * 32 + lhi * 8);
#pragma unroll
            for (int jd = 0; jd < 4; jd++) {
                const bf16x8 bv = *(const bf16x8*)(Vs + sw8(jd * 16 + llo, kk * 4 + lhi));
                accO[0][jd] = __builtin_amdgcn_mfma_f32_16x16x32_bf16(ap[0], bv, accO[0][jd], 0, 0, 0);
                accO[1][jd] = __builtin_amdgcn_mfma_f32_16x16x32_bf16(ap[1], bv, accO[1][jd], 0, 0, 0);
            }
        }
    };

    for (int m0 = 0; m0 < 2048; m0 += 128) {
        body(m0, mvA, mvB);
        body(m0 + 64, mvB, mvA);
    }

    // reduce l over the 16 columns, epilogue leaky_relu(O/l)
#pragma unroll
    for (int i = 0; i < 2; i++)
#pragma unroll
        for (int r = 0; r < 4; r++) {
#pragma unroll
            for (int o = 1; o < 16; o <<= 1) lsum[i][r] += __shfl_xor(lsum[i][r], o);
            lsum[i][r] = 1.0f / lsum[i][r];
        }
#pragma unroll
    for (int i = 0; i < 2; i++)
#pragma unroll
        for (int jd = 0; jd < 4; jd++)
#pragma unroll
            for (int r = 0; r < 4; r++) {
                float v = accO[i][jd][r] * lsum[i][r];
                v = v >= 0.f ? v : 0.01f * v;
                const int q = q0 + wave * 32 + i * 16 + lhi * 4 + r;
                attnL[((size_t)b * 2048 + q) * 1024 + hh * 64 + jd * 16 + llo] = f2bf(v);
            }
}

// ---------------- launcher ----------------
extern "C" void kernel_launch(void* const* d_in, const int* in_sizes, int n_in,
                              void* d_out, int out_size, void* d_ws, size_t ws_size,
                              hipStream_t stream) {
    const float* Z     = (const float*)d_in[0];
    const float* nmask = (const float*)d_in[1];
    const float* pmask = (const float*)d_in[2];
    const float* ln1_g = (const float*)d_in[3];
    const float* ln1_b = (const float*)d_in[4];
    const float* qkv_w = (const float*)d_in[5];
    const float* qkv_b = (const float*)d_in[6];
    const float* o_w   = (const float*)d_in[7];
    const float* ln2_g = (const float*)d_in[8];
    const float* ln2_b = (const float*)d_in[9];
    const float* p1_w  = (const float*)d_in[10];
    const float* p1_b  = (const float*)d_in[11];
    const float* p2_w  = (const float*)d_in[12];
    const float* p2_b  = (const float*)d_in[13];
    float* out = (float*)d_out;

    char* w = (char*)d_ws;
    auto take = [&](size_t bytes) -> char* {
        char* p = w;
        w += (bytes + 255) & ~(size_t)255;
        return p;
    };
    u16* qkvW   = (u16*)take((size_t)3072 * 1024 * 2);
    u16* oW     = (u16*)take((size_t)1024 * 1024 * 2);
    u16* p1W    = (u16*)take((size_t)4096 * 1024 * 2);
    u16* p2W    = (u16*)take((size_t)1024 * 4096 * 2);
    u16* Zn     = (u16*)take((size_t)4096 * 1024 * 2);   // reused for Zn2
    u16* Qb     = (u16*)take((size_t)32 * 2048 * 64 * 2);
    u16* Kb     = (u16*)take((size_t)32 * 2048 * 64 * 2);
    u16* Vt     = (u16*)take((size_t)32 * 64 * 2048 * 2);
    u16* attnL  = (u16*)take((size_t)4096 * 1024 * 2);
    float* Z1   = (float*)take((size_t)4096 * 1024 * 4);
    u16* hbuf   = (u16*)take((size_t)4096 * 4096 * 2);
    unsigned* Mp = (unsigned*)take((size_t)2 * 2048 * 2048 * 4);
    float* pbias = (float*)take((size_t)3072 * 4);
    float* Vsc   = (float*)hbuf;  // alias: Vsc dead before hbuf is written

    // weight prep
    cast_qkv<<<dim3(3072), 256, 0, stream>>>(qkv_w, qkvW);
    permute_bias<<<dim3(12), 256, 0, stream>>>(qkv_b, pbias);
    cast_bf16<<<dim3(1024), 256, 0, stream>>>(o_w, oW, 1024 * 1024 / 4);
    cast_bf16<<<dim3(4096), 256, 0, stream>>>(p1_w, p1W, 4096 * 1024 / 4);
    cast_bf16<<<dim3(4096), 256, 0, stream>>>(p2_w, p2W, 1024 * 4096 / 4);
    pack_mask<<<dim3(8192), 256, 0, stream>>>(nmask, pmask, Mp, 2 * 2048 * 2048 / 4);

    // LN1
    ln_bf16<<<dim3(4096), 256, 0, stream>>>(Z, ln1_g, ln1_b, Zn);
    // QKV projection: V -> f32 scratch, Q/K -> bf16 [BH][N][64]
    gemm_bt<0, 128><<<dim3(24, 32), 256, 0, stream>>>(Zn, qkvW, pbias, nullptr, Vsc, Qb, Kb, 4096, 3072, 1024);
    // V transpose -> Vt [BH][64][2048]
    vtrans<<<dim3(32, 32), 256, 0, stream>>>(Vsc, Vt);
    // attention
    attn_fused3<<<dim3(512), 256, 0, stream>>>(Qb, Kb, Vt, Mp, attnL);
    // o-projection + residual  (BN=64 -> 512 blocks, 2/CU)
    gemm_bt<1, 64><<<dim3(16, 32), 256, 0, stream>>>(attnL, oW, nullptr, Z, Z1, nullptr, nullptr, 4096, 1024, 1024);
    // LN2
    ln_bf16<<<dim3(4096), 256, 0, stream>>>(Z1, ln2_g, ln2_b, Zn);
    // MLP up + relu
    gemm_bt<2, 128><<<dim3(32, 32), 256, 0, stream>>>(Zn, p1W, p1_b, nullptr, hbuf, nullptr, nullptr, 4096, 4096, 1024);
    // MLP down + bias + residual -> out  (BN=64 -> 512 blocks, 2/CU)
    gemm_bt<3, 64><<<dim3(16, 32), 256, 0, stream>>>(hbuf, p2W, p2_b, Z1, out, nullptr, nullptr, 4096, 1024, 4096);
}

// Round 4
// 445.513 us; speedup vs baseline: 1.3891x; 1.0666x over previous
//
#include <hip/hip_runtime.h>

typedef unsigned short u16;
typedef __attribute__((ext_vector_type(8))) short bf16x8;
typedef __attribute__((ext_vector_type(4))) float f32x4;

#define DEV static __device__ __forceinline__

DEV u16 f2bf(float f) {
    unsigned u = __float_as_uint(f);
    u += 0x7FFFu + ((u >> 16) & 1u);
    return (u16)(u >> 16);
}

typedef const __attribute__((address_space(1))) void* gas1_t;
typedef __attribute__((address_space(3))) void* gas3_t;

DEV void gl_lds16(const u16* g, u16* l) {
    __builtin_amdgcn_global_load_lds((gas1_t)g, (gas3_t)l, 16, 0, 0);
}

// swizzled LDS offset (u16 units) for 128B rows of 64 u16, 16B chunks
DEV int sw8(int row, int chunk) { return row * 64 + ((chunk ^ (row & 7)) << 3); }

// ---------------- elementwise f32 -> bf16 cast (weights) ----------------
__global__ void cast_bf16(const float* __restrict__ in, u16* __restrict__ out, int n4) {
    int i = blockIdx.x * blockDim.x + threadIdx.x;
    if (i < n4) {
        float4 v = ((const float4*)in)[i];
        ushort4 o;
        o.x = f2bf(v.x); o.y = f2bf(v.y); o.z = f2bf(v.z); o.w = f2bf(v.w);
        ((ushort4*)out)[i] = o;
    }
}

// qkv weight: cast + row permutation so out rows = [V(1024) | Q(1024) | K(1024)]
__global__ void cast_qkv(const float* __restrict__ in, u16* __restrict__ out) {
    int i = blockIdx.x * 256 + threadIdx.x;   // 3072*256 float4s
    int orow = i >> 8, cc = i & 255;
    int region = orow >> 10, rem = orow & 1023, h = rem >> 6, t = rem & 63;
    int srow = h * 192 + region * 64 + t;
    float4 v = ((const float4*)in)[srow * 256 + cc];
    ushort4 o;
    o.x = f2bf(v.x); o.y = f2bf(v.y); o.z = f2bf(v.z); o.w = f2bf(v.w);
    ((ushort4*)out)[i] = o;
}

__global__ void permute_bias(const float* __restrict__ in, float* __restrict__ out) {
    int i = blockIdx.x * 256 + threadIdx.x;
    if (i < 3072) {
        int region = i >> 10, rem = i & 1023, h = rem >> 6, t = rem & 63;
        out[i] = in[h * 192 + region * 64 + t];
    }
}

// pack masks: u32 = (bf16(pmask) << 16) | bf16(nmask * log2(e))
__global__ void pack_mask(const float* __restrict__ nm, const float* __restrict__ pm,
                          unsigned* __restrict__ out, int n4) {
    int i = blockIdx.x * blockDim.x + threadIdx.x;
    if (i < n4) {
        float4 a = ((const float4*)nm)[i];
        float4 b = ((const float4*)pm)[i];
        uint4 o;
        o.x = ((unsigned)f2bf(b.x) << 16) | f2bf(a.x * 1.4426950f);
        o.y = ((unsigned)f2bf(b.y) << 16) | f2bf(a.y * 1.4426950f);
        o.z = ((unsigned)f2bf(b.z) << 16) | f2bf(a.z * 1.4426950f);
        o.w = ((unsigned)f2bf(b.w) << 16) | f2bf(a.w * 1.4426950f);
        ((uint4*)out)[i] = o;
    }
}

// ---------------- LayerNorm (D=1024) f32 -> bf16 ----------------
__global__ __launch_bounds__(256) void ln_bf16(const float* __restrict__ x,
                                               const float* __restrict__ gam,
                                               const float* __restrict__ bet,
                                               u16* __restrict__ y) {
    const int row = blockIdx.x;
    const int t = threadIdx.x;
    const float4 v = ((const float4*)(x + (size_t)row * 1024))[t];
    float s = v.x + v.y + v.z + v.w;
    float ss = v.x * v.x + v.y * v.y + v.z * v.z + v.w * v.w;
#pragma unroll
    for (int o = 1; o < 64; o <<= 1) {
        s += __shfl_xor(s, o);
        ss += __shfl_xor(ss, o);
    }
    __shared__ float rs[4], rss[4];
    const int wave = t >> 6, lane = t & 63;
    if (lane == 0) { rs[wave] = s; rss[wave] = ss; }
    __syncthreads();
    const float tot = rs[0] + rs[1] + rs[2] + rs[3];
    const float totss = rss[0] + rss[1] + rss[2] + rss[3];
    const float mu = tot * (1.0f / 1024.0f);
    const float var = totss * (1.0f / 1024.0f) - mu * mu;
    const float rstd = rsqrtf(var + 1e-5f);
    const float4 g4 = ((const float4*)gam)[t];
    const float4 b4 = ((const float4*)bet)[t];
    ushort4 o;
    o.x = f2bf((v.x - mu) * rstd * g4.x + b4.x);
    o.y = f2bf((v.y - mu) * rstd * g4.y + b4.y);
    o.z = f2bf((v.z - mu) * rstd * g4.z + b4.z);
    o.w = f2bf((v.w - mu) * rstd * g4.w + b4.w);
    ((ushort4*)(y + (size_t)row * 1024))[t] = o;
}

// ---- fused combine + LayerNorm: Z1 = p0+p1+Z ; write Z1 f32 and LN(Z1) bf16 ----
__global__ __launch_bounds__(256) void ln2_comb(const float* __restrict__ p0,
                                                const float* __restrict__ p1,
                                                const float* __restrict__ Z,
                                                const float* __restrict__ gam,
                                                const float* __restrict__ bet,
                                                float* __restrict__ Z1,
                                                u16* __restrict__ y) {
    const int row = blockIdx.x;
    const int t = threadIdx.x;
    const float4 a = ((const float4*)(p0 + (size_t)row * 1024))[t];
    const float4 c = ((const float4*)(p1 + (size_t)row * 1024))[t];
    const float4 z = ((const float4*)(Z + (size_t)row * 1024))[t];
    float4 v;
    v.x = a.x + c.x + z.x; v.y = a.y + c.y + z.y;
    v.z = a.z + c.z + z.z; v.w = a.w + c.w + z.w;
    ((float4*)(Z1 + (size_t)row * 1024))[t] = v;
    float s = v.x + v.y + v.z + v.w;
    float ss = v.x * v.x + v.y * v.y + v.z * v.z + v.w * v.w;
#pragma unroll
    for (int o = 1; o < 64; o <<= 1) {
        s += __shfl_xor(s, o);
        ss += __shfl_xor(ss, o);
    }
    __shared__ float rs[4], rss[4];
    const int wave = t >> 6, lane = t & 63;
    if (lane == 0) { rs[wave] = s; rss[wave] = ss; }
    __syncthreads();
    const float tot = rs[0] + rs[1] + rs[2] + rs[3];
    const float totss = rss[0] + rss[1] + rss[2] + rss[3];
    const float mu = tot * (1.0f / 1024.0f);
    const float var = totss * (1.0f / 1024.0f) - mu * mu;
    const float rstd = rsqrtf(var + 1e-5f);
    const float4 g4 = ((const float4*)gam)[t];
    const float4 b4 = ((const float4*)bet)[t];
    ushort4 o;
    o.x = f2bf((v.x - mu) * rstd * g4.x + b4.x);
    o.y = f2bf((v.y - mu) * rstd * g4.y + b4.y);
    o.z = f2bf((v.z - mu) * rstd * g4.z + b4.z);
    o.w = f2bf((v.w - mu) * rstd * g4.w + b4.w);
    ((ushort4*)(y + (size_t)row * 1024))[t] = o;
}

// ---- final combine: out = p0 + p1 + bias + Z1 ----
__global__ __launch_bounds__(256) void out_comb(const float* __restrict__ p0,
                                                const float* __restrict__ p1,
                                                const float* __restrict__ bias,
                                                const float* __restrict__ Z1,
                                                float* __restrict__ out) {
    int i = blockIdx.x * 256 + threadIdx.x;   // 1048576 float4s
    float4 a = ((const float4*)p0)[i];
    float4 c = ((const float4*)p1)[i];
    float4 z = ((const float4*)Z1)[i];
    float4 b = ((const float4*)bias)[i & 255];
    float4 o;
    o.x = a.x + c.x + z.x + b.x; o.y = a.y + c.y + z.y + b.y;
    o.z = a.z + c.z + z.z + b.z; o.w = a.w + c.w + z.w + b.w;
    ((float4*)out)[i] = o;
}

// ---------------- GEMM: C[M,N] = A[M,K-slice] @ Bt[N,K-slice]^T ----------------
// 128x128 tile, BK=32. ldk = row stride of A and Bt; K = slice length;
// slice start = blockIdx.z * K.
// EPI 0: +pbias; region: 0 -> f32 Vsc, 1 -> Q bf16, 2 -> K bf16
// EPI 2: +bias, relu, write bf16 out0
// EPI 4: raw f32 partial -> out0 + z*M*N
template <int EPI>
__global__ __launch_bounds__(256, 2) void gemm_bt(const u16* __restrict__ A,
                                                  const u16* __restrict__ Bt,
                                                  const float* __restrict__ bias,
                                                  void* __restrict__ out0,
                                                  void* __restrict__ out1,
                                                  void* __restrict__ out2,
                                                  int M, int N, int K, int ldk) {
    __shared__ __align__(16) u16 As[128 * 32];
    __shared__ __align__(16) u16 Bs[128 * 32];
    const int tid = threadIdx.x;
    const int wave = tid >> 6, lane = tid & 63;
    const int lhi = lane >> 4, llo = lane & 15;
    const int bx = blockIdx.x, by = blockIdx.y;
    const int kz = blockIdx.z * K;

    const int arow = wave * 32 + (lane >> 2);
    const int acol = (lane & 3) * 8;
    const u16* gA = A + (size_t)(by * 128 + arow) * ldk + kz + acol;
    const u16* gB = Bt + (size_t)(bx * 128 + arow) * ldk + kz + acol;
    u16* lA = As + wave * 1024 + lane * 8;
    u16* lB = Bs + wave * 1024 + lane * 8;

    const int wr = wave >> 1, wc = wave & 1;
    const f32x4 zero = {0.f, 0.f, 0.f, 0.f};
    f32x4 acc[4][4];
#pragma unroll
    for (int i = 0; i < 4; i++)
#pragma unroll
        for (int j = 0; j < 4; j++) acc[i][j] = zero;

    for (int k0 = 0; k0 < K; k0 += 32) {
        __syncthreads();
        gl_lds16(gA, lA);
        gl_lds16(gA + 16 * (size_t)ldk, lA + 512);
        gl_lds16(gB, lB);
        gl_lds16(gB + 16 * (size_t)ldk, lB + 512);
        gA += 32; gB += 32;
        __syncthreads();
        bf16x8 af[4], bfr[4];
#pragma unroll
        for (int i = 0; i < 4; i++)
            af[i] = *(const bf16x8*)(As + (wr * 64 + i * 16 + llo) * 32 + lhi * 8);
#pragma unroll
        for (int j = 0; j < 4; j++)
            bfr[j] = *(const bf16x8*)(Bs + (wc * 64 + j * 16 + llo) * 32 + lhi * 8);
#pragma unroll
        for (int i = 0; i < 4; i++)
#pragma unroll
            for (int j = 0; j < 4; j++)
                acc[i][j] = __builtin_amdgcn_mfma_f32_16x16x32_bf16(af[i], bfr[j], acc[i][j], 0, 0, 0);
    }

    const int rbase = by * 128 + wr * 64 + lhi * 4;
    const int cbase = bx * 128 + wc * 64 + llo;
    float* pout = (EPI == 4) ? ((float*)out0 + (size_t)blockIdx.z * M * N) : (float*)out0;
#pragma unroll
    for (int i = 0; i < 4; i++) {
#pragma unroll
        for (int j = 0; j < 4; j++) {
#pragma unroll
            for (int r = 0; r < 4; r++) {
                const int row = rbase + i * 16 + r;
                const int col = cbase + j * 16;
                float v = acc[i][j][r];
                if constexpr (EPI == 0) {
                    v += bias[col];
                    const int region = col >> 10;   // uniform per block
                    const int c = col & 1023;       // h*64 + t
                    const int b = row >> 11, n = row & 2047;
                    if (region == 0) {
                        ((float*)out0)[(size_t)row * 1024 + c] = v;  // Vsc f32
                    } else {
                        const int h = c >> 6, t = c & 63;
                        u16* dst = (region == 1) ? (u16*)out1 : (u16*)out2;
                        dst[(((size_t)(b * 16 + h)) * 2048 + n) * 64 + t] = f2bf(v);
                    }
                } else if constexpr (EPI == 2) {
                    v += bias[col];
                    v = v > 0.f ? v : 0.f;
                    ((u16*)out0)[(size_t)row * N + col] = f2bf(v);
                } else {
                    pout[(size_t)row * N + col] = v;
                }
            }
        }
    }
}

// ---------------- V transpose: Vsc f32 [B*N][1024] -> Vt bf16 [BH][64][2048] --
__global__ __launch_bounds__(256) void vtrans(const float* __restrict__ Vsc,
                                              u16* __restrict__ Vt) {
    __shared__ u16 Ts[64 * 72];
    const int nt = blockIdx.x;  // n-tile (0..31)
    const int bh = blockIdx.y;  // 0..31
    const int b = bh >> 4, h = bh & 15;
    const int t = threadIdx.x;
    const int n0 = nt * 64;
    const int nr = t >> 2;
    const int dq = (t & 3) * 16;
    const float* src = Vsc + ((size_t)(b * 2048 + n0 + nr)) * 1024 + h * 64 + dq;
    float4 v0 = ((const float4*)src)[0];
    float4 v1 = ((const float4*)src)[1];
    float4 v2 = ((const float4*)src)[2];
    float4 v3 = ((const float4*)src)[3];
    u16* c0 = Ts + nr;
    c0[(dq + 0) * 72]  = f2bf(v0.x); c0[(dq + 1) * 72]  = f2bf(v0.y);
    c0[(dq + 2) * 72]  = f2bf(v0.z); c0[(dq + 3) * 72]  = f2bf(v0.w);
    c0[(dq + 4) * 72]  = f2bf(v1.x); c0[(dq + 5) * 72]  = f2bf(v1.y);
    c0[(dq + 6) * 72]  = f2bf(v1.z); c0[(dq + 7) * 72]  = f2bf(v1.w);
    c0[(dq + 8) * 72]  = f2bf(v2.x); c0[(dq + 9) * 72]  = f2bf(v2.y);
    c0[(dq + 10) * 72] = f2bf(v2.z); c0[(dq + 11) * 72] = f2bf(v2.w);
    c0[(dq + 12) * 72] = f2bf(v3.x); c0[(dq + 13) * 72] = f2bf(v3.y);
    c0[(dq + 14) * 72] = f2bf(v3.z); c0[(dq + 15) * 72] = f2bf(v3.w);
    __syncthreads();
    const int d = t >> 2, n8 = (t & 3) * 16;
    bf16x8 o0 = *(const bf16x8*)(Ts + d * 72 + n8);
    bf16x8 o1 = *(const bf16x8*)(Ts + d * 72 + n8 + 8);
    u16* dst = Vt + ((size_t)bh * 64 + d) * 2048 + n0 + n8;
    *(bf16x8*)dst = o0;
    *(bf16x8*)(dst + 8) = o1;
}

// ---------------- fused flash-style attention v4 ----------------
// grid 1024, id = hh*64 + b*32 + qt  (mask-sharing blocks on same XCD).
// q-tile 64 (wave owns 16 q-rows), m-tile 64, 4 blocks/CU.
// One-pass softmax; Ps padded stride-72.
__global__ __launch_bounds__(256, 4) void attn_fused4(const u16* __restrict__ Qg,
                                                      const u16* __restrict__ Kg,
                                                      const u16* __restrict__ Vt,
                                                      const unsigned* __restrict__ Mp,
                                                      u16* __restrict__ attnL) {
    __shared__ __align__(16) u16 Qs[64 * 64];
    __shared__ __align__(16) u16 Ks[64 * 64];
    __shared__ __align__(16) u16 Vs[64 * 64];   // [d][m]
    __shared__ __align__(16) u16 Ps[64 * 72];   // padded rows
    const int tid = threadIdx.x, wave = tid >> 6, lane = tid & 63;
    const int lhi = lane >> 4, llo = lane & 15;
    const int id = blockIdx.x;
    const int hh = id >> 6, rem = id & 63;
    const int b = rem >> 5, qt = rem & 31;
    const int bh = b * 16 + hh;
    const int q0 = qt * 64;
    const int l3 = lane >> 3, l7 = lane & 7;
    const int swcol = (l7 ^ (l3 & 7)) * 8;   // swizzled source column (u16)

    // stage Q tile (64 rows) once
#pragma unroll
    for (int s = 0; s < 2; s++) {
        const int row = wave * 16 + s * 8 + l3;
        gl_lds16(Qg + ((size_t)bh * 2048 + q0 + row) * 64 + swcol,
                 Qs + wave * 1024 + s * 512 + lane * 8);
    }

    const unsigned* Mpb = Mp + (size_t)b * 2048 * 2048;
    int midx[4];
#pragma unroll
    for (int r = 0; r < 4; r++)
        midx[r] = (q0 + wave * 16 + lhi * 4 + r) * 2048 + llo;

    const f32x4 zero = {0.f, 0.f, 0.f, 0.f};
    f32x4 accO[4];
    float lsum[4];
#pragma unroll
    for (int j = 0; j < 4; j++) accO[j] = zero;
#pragma unroll
    for (int r = 0; r < 4; r++) lsum[r] = 0.f;

    const float CS = 0.125f * 1.4426950f;
    const int pb0 = (wave * 16 + lhi * 4) * 72 + llo;

    for (int m0 = 0; m0 < 2048; m0 += 64) {
        __syncthreads();
        // stage K[m0..m0+64) and Vt[:, m0..m0+64) (swizzled)
#pragma unroll
        for (int s = 0; s < 2; s++) {
            const int row = wave * 16 + s * 8 + l3;
            gl_lds16(Kg + ((size_t)bh * 2048 + m0 + row) * 64 + swcol,
                     Ks + wave * 1024 + s * 512 + lane * 8);
            gl_lds16(Vt + ((size_t)bh * 64 + row) * 2048 + m0 + swcol,
                     Vs + wave * 1024 + s * 512 + lane * 8);
        }
        // mask loads ride the same latency window; ready at the barrier
        unsigned mv[4][4];
#pragma unroll
        for (int r = 0; r < 4; r++)
#pragma unroll
            for (int j = 0; j < 4; j++) mv[r][j] = Mpb[midx[r] + m0 + j * 16];
        __syncthreads();

        // S = Q K^T  (wave's 16 q-rows x 64 m-cols)
        f32x4 sacc[4];
#pragma unroll
        for (int j = 0; j < 4; j++) sacc[j] = zero;
#pragma unroll
        for (int kk = 0; kk < 2; kk++) {
            const bf16x8 aq = *(const bf16x8*)(Qs + sw8(wave * 16 + llo, kk * 4 + lhi));
#pragma unroll
            for (int j = 0; j < 4; j++) {
                const bf16x8 bk = *(const bf16x8*)(Ks + sw8(j * 16 + llo, kk * 4 + lhi));
                sacc[j] = __builtin_amdgcn_mfma_f32_16x16x32_bf16(aq, bk, sacc[j], 0, 0, 0);
            }
        }

        // P = exp2(S*CS + nm) * pm ; l += exp (unmasked denominator)
#pragma unroll
        for (int j = 0; j < 4; j++)
#pragma unroll
            for (int r = 0; r < 4; r++) {
                const unsigned u = mv[r][j];
                const float nm = __uint_as_float(u << 16);
                const float pm = __uint_as_float(u & 0xFFFF0000u);
                const float e = exp2f(fmaf(sacc[j][r], CS, nm));
                lsum[r] += e;
                const float p = e * pm;
                Ps[pb0 + r * 72 + j * 16] = (u16)((__float_as_uint(p) + 0x8000u) >> 16);
            }

        // O += P @ V  (Ps rows wave-private)
#pragma unroll
        for (int kk = 0; kk < 2; kk++) {
            const bf16x8 ap = *(const bf16x8*)(Ps + (wave * 16 + llo) * 72 + kk * 32 + lhi * 8);
#pragma unroll
            for (int jd = 0; jd < 4; jd++) {
                const bf16x8 bv = *(const bf16x8*)(Vs + sw8(jd * 16 + llo, kk * 4 + lhi));
                accO[jd] = __builtin_amdgcn_mfma_f32_16x16x32_bf16(ap, bv, accO[jd], 0, 0, 0);
            }
        }
    }

    // reduce l over the 16 llo-lanes, epilogue leaky_relu(O/l)
#pragma unroll
    for (int r = 0; r < 4; r++) {
#pragma unroll
        for (int o = 1; o < 16; o <<= 1) lsum[r] += __shfl_xor(lsum[r], o);
        lsum[r] = 1.0f / lsum[r];
    }
#pragma unroll
    for (int jd = 0; jd < 4; jd++)
#pragma unroll
        for (int r = 0; r < 4; r++) {
            float v = accO[jd][r] * lsum[r];
            v = v >= 0.f ? v : 0.01f * v;
            const int q = q0 + wave * 16 + lhi * 4 + r;
            attnL[((size_t)b * 2048 + q) * 1024 + hh * 64 + jd * 16 + llo] = f2bf(v);
        }
}

// ---------------- launcher ----------------
extern "C" void kernel_launch(void* const* d_in, const int* in_sizes, int n_in,
                              void* d_out, int out_size, void* d_ws, size_t ws_size,
                              hipStream_t stream) {
    const float* Z     = (const float*)d_in[0];
    const float* nmask = (const float*)d_in[1];
    const float* pmask = (const float*)d_in[2];
    const float* ln1_g = (const float*)d_in[3];
    const float* ln1_b = (const float*)d_in[4];
    const float* qkv_w = (const float*)d_in[5];
    const float* qkv_b = (const float*)d_in[6];
    const float* o_w   = (const float*)d_in[7];
    const float* ln2_g = (const float*)d_in[8];
    const float* ln2_b = (const float*)d_in[9];
    const float* p1_w  = (const float*)d_in[10];
    const float* p1_b  = (const float*)d_in[11];
    const float* p2_w  = (const float*)d_in[12];
    const float* p2_b  = (const float*)d_in[13];
    float* out = (float*)d_out;

    char* w = (char*)d_ws;
    auto take = [&](size_t bytes) -> char* {
        char* p = w;
        w += (bytes + 255) & ~(size_t)255;
        return p;
    };
    u16* qkvW   = (u16*)take((size_t)3072 * 1024 * 2);
    u16* oW     = (u16*)take((size_t)1024 * 1024 * 2);
    u16* p1W    = (u16*)take((size_t)4096 * 1024 * 2);
    u16* p2W    = (u16*)take((size_t)1024 * 4096 * 2);
    u16* Zn     = (u16*)take((size_t)4096 * 1024 * 2);   // reused for Zn2
    u16* Qb     = (u16*)take((size_t)32 * 2048 * 64 * 2);
    u16* Kb     = (u16*)take((size_t)32 * 2048 * 64 * 2);
    u16* Vt     = (u16*)take((size_t)32 * 64 * 2048 * 2);
    u16* attnL  = (u16*)take((size_t)4096 * 1024 * 2);
    float* Z1   = (float*)take((size_t)4096 * 1024 * 4);
    u16* hbuf   = (u16*)take((size_t)4096 * 4096 * 2);
    unsigned* Mp = (unsigned*)take((size_t)2 * 2048 * 2048 * 4);
    float* pbias = (float*)take((size_t)3072 * 4);
    float* Vsc   = (float*)hbuf;          // alias: Vsc dead before hbuf written
    float* part  = (float*)Mp;            // alias: Mp dead after attention
    float* part1 = part + (size_t)4096 * 1024;

    // weight prep
    cast_qkv<<<dim3(3072), 256, 0, stream>>>(qkv_w, qkvW);
    permute_bias<<<dim3(12), 256, 0, stream>>>(qkv_b, pbias);
    cast_bf16<<<dim3(1024), 256, 0, stream>>>(o_w, oW, 1024 * 1024 / 4);
    cast_bf16<<<dim3(4096), 256, 0, stream>>>(p1_w, p1W, 4096 * 1024 / 4);
    cast_bf16<<<dim3(4096), 256, 0, stream>>>(p2_w, p2W, 1024 * 4096 / 4);
    pack_mask<<<dim3(8192), 256, 0, stream>>>(nmask, pmask, Mp, 2 * 2048 * 2048 / 4);

    // LN1
    ln_bf16<<<dim3(4096), 256, 0, stream>>>(Z, ln1_g, ln1_b, Zn);
    // QKV projection: V -> f32 scratch, Q/K -> bf16 [BH][N][64]
    gemm_bt<0><<<dim3(24, 32), 256, 0, stream>>>(Zn, qkvW, pbias, Vsc, Qb, Kb, 4096, 3072, 1024, 1024);
    // V transpose -> Vt [BH][64][2048]
    vtrans<<<dim3(32, 32), 256, 0, stream>>>(Vsc, Vt);
    // attention (4 blocks/CU)
    attn_fused4<<<dim3(1024), 256, 0, stream>>>(Qb, Kb, Vt, Mp, attnL);
    // o-projection, split-K=2 -> f32 partials
    gemm_bt<4><<<dim3(8, 32, 2), 256, 0, stream>>>(attnL, oW, nullptr, part, nullptr, nullptr, 4096, 1024, 512, 1024);
    // combine + residual + LN2 (writes Z1 and Zn)
    ln2_comb<<<dim3(4096), 256, 0, stream>>>(part, part1, Z, ln2_g, ln2_b, Z1, Zn);
    // MLP up + relu
    gemm_bt<2><<<dim3(32, 32), 256, 0, stream>>>(Zn, p1W, p1_b, hbuf, nullptr, nullptr, 4096, 4096, 1024, 1024);
    // MLP down, split-K=2 -> f32 partials
    gemm_bt<4><<<dim3(8, 32, 2), 256, 0, stream>>>(hbuf, p2W, nullptr, part, nullptr, nullptr, 4096, 1024, 2048, 4096);
    // final combine -> out
    out_comb<<<dim3(4096), 256, 0, stream>>>(part, part1, p2_b, Z1, out);
}

// Round 5
// 443.787 us; speedup vs baseline: 1.3945x; 1.0039x over previous
//
#include <hip/hip_runtime.h>

typedef unsigned short u16;
typedef __attribute__((ext_vector_type(8))) short bf16x8;
typedef __attribute__((ext_vector_type(4))) float f32x4;

#define DEV static __device__ __forceinline__

DEV u16 f2bf(float f) {
    unsigned u = __float_as_uint(f);
    u += 0x7FFFu + ((u >> 16) & 1u);
    return (u16)(u >> 16);
}

typedef const __attribute__((address_space(1))) void* gas1_t;
typedef __attribute__((address_space(3))) void* gas3_t;

DEV void gl_lds16(const u16* g, u16* l) {
    __builtin_amdgcn_global_load_lds((gas1_t)g, (gas3_t)l, 16, 0, 0);
}

// swizzled LDS offset (u16 units) for 128B rows of 64 u16, 16B chunks
DEV int sw8(int row, int chunk) { return row * 64 + ((chunk ^ (row & 7)) << 3); }

// ---------------- merged prep: weight casts + bias permute + mask pack ----------------
// block ranges: [0,3072) qkvW | [3072,4096) oW | [4096,8192) p1W | [8192,12288) p2W
//               | [12288,20480) mask pack | 20480 pbias
__global__ __launch_bounds__(256) void prep_all(const float* __restrict__ qkv_w,
                                                const float* __restrict__ o_w,
                                                const float* __restrict__ p1_w,
                                                const float* __restrict__ p2_w,
                                                const float* __restrict__ qkv_b,
                                                const float* __restrict__ nm,
                                                const float* __restrict__ pm,
                                                u16* __restrict__ qkvW,
                                                u16* __restrict__ oW,
                                                u16* __restrict__ p1W,
                                                u16* __restrict__ p2W,
                                                float* __restrict__ pbias,
                                                unsigned* __restrict__ Mp) {
    const int bid = blockIdx.x, t = threadIdx.x;
    if (bid < 3072) {            // qkv cast + row permute: rows = [V|Q|K], each h*64+t
        int i = bid * 256 + t;
        int orow = i >> 8, cc = i & 255;
        int region = orow >> 10, rem = orow & 1023, h = rem >> 6, tt = rem & 63;
        int srow = h * 192 + region * 64 + tt;
        float4 v = ((const float4*)qkv_w)[srow * 256 + cc];
        ushort4 o;
        o.x = f2bf(v.x); o.y = f2bf(v.y); o.z = f2bf(v.z); o.w = f2bf(v.w);
        ((ushort4*)qkvW)[i] = o;
    } else if (bid < 4096) {     // o_w cast
        int i = (bid - 3072) * 256 + t;
        float4 v = ((const float4*)o_w)[i];
        ushort4 o;
        o.x = f2bf(v.x); o.y = f2bf(v.y); o.z = f2bf(v.z); o.w = f2bf(v.w);
        ((ushort4*)oW)[i] = o;
    } else if (bid < 8192) {     // p1_w cast
        int i = (bid - 4096) * 256 + t;
        float4 v = ((const float4*)p1_w)[i];
        ushort4 o;
        o.x = f2bf(v.x); o.y = f2bf(v.y); o.z = f2bf(v.z); o.w = f2bf(v.w);
        ((ushort4*)p1W)[i] = o;
    } else if (bid < 12288) {    // p2_w cast
        int i = (bid - 8192) * 256 + t;
        float4 v = ((const float4*)p2_w)[i];
        ushort4 o;
        o.x = f2bf(v.x); o.y = f2bf(v.y); o.z = f2bf(v.z); o.w = f2bf(v.w);
        ((ushort4*)p2W)[i] = o;
    } else if (bid < 20480) {    // mask pack: u32 = bf16(pm)<<16 | bf16(nm*log2e)
        int i = (bid - 12288) * 256 + t;
        float4 a = ((const float4*)nm)[i];
        float4 b = ((const float4*)pm)[i];
        uint4 o;
        o.x = ((unsigned)f2bf(b.x) << 16) | f2bf(a.x * 1.4426950f);
        o.y = ((unsigned)f2bf(b.y) << 16) | f2bf(a.y * 1.4426950f);
        o.z = ((unsigned)f2bf(b.z) << 16) | f2bf(a.z * 1.4426950f);
        o.w = ((unsigned)f2bf(b.w) << 16) | f2bf(a.w * 1.4426950f);
        ((uint4*)Mp)[i] = o;
    } else {                     // qkv bias permute (3072 elements)
#pragma unroll
        for (int k = 0; k < 12; k++) {
            int i = k * 256 + t;
            int region = i >> 10, rem = i & 1023, h = rem >> 6, tt = rem & 63;
            pbias[i] = qkv_b[h * 192 + region * 64 + tt];
        }
    }
}

// ---------------- LayerNorm (D=1024) f32 -> bf16 ----------------
__global__ __launch_bounds__(256) void ln_bf16(const float* __restrict__ x,
                                               const float* __restrict__ gam,
                                               const float* __restrict__ bet,
                                               u16* __restrict__ y) {
    const int row = blockIdx.x;
    const int t = threadIdx.x;
    const float4 v = ((const float4*)(x + (size_t)row * 1024))[t];
    float s = v.x + v.y + v.z + v.w;
    float ss = v.x * v.x + v.y * v.y + v.z * v.z + v.w * v.w;
#pragma unroll
    for (int o = 1; o < 64; o <<= 1) {
        s += __shfl_xor(s, o);
        ss += __shfl_xor(ss, o);
    }
    __shared__ float rs[4], rss[4];
    const int wave = t >> 6, lane = t & 63;
    if (lane == 0) { rs[wave] = s; rss[wave] = ss; }
    __syncthreads();
    const float tot = rs[0] + rs[1] + rs[2] + rs[3];
    const float totss = rss[0] + rss[1] + rss[2] + rss[3];
    const float mu = tot * (1.0f / 1024.0f);
    const float var = totss * (1.0f / 1024.0f) - mu * mu;
    const float rstd = rsqrtf(var + 1e-5f);
    const float4 g4 = ((const float4*)gam)[t];
    const float4 b4 = ((const float4*)bet)[t];
    ushort4 o;
    o.x = f2bf((v.x - mu) * rstd * g4.x + b4.x);
    o.y = f2bf((v.y - mu) * rstd * g4.y + b4.y);
    o.z = f2bf((v.z - mu) * rstd * g4.z + b4.z);
    o.w = f2bf((v.w - mu) * rstd * g4.w + b4.w);
    ((ushort4*)(y + (size_t)row * 1024))[t] = o;
}

// ---- fused 4-way combine + residual + LayerNorm ----
__global__ __launch_bounds__(256) void ln2_comb4(const float* __restrict__ p0,
                                                 const float* __restrict__ p1,
                                                 const float* __restrict__ p2,
                                                 const float* __restrict__ p3,
                                                 const float* __restrict__ Z,
                                                 const float* __restrict__ gam,
                                                 const float* __restrict__ bet,
                                                 float* __restrict__ Z1,
                                                 u16* __restrict__ y) {
    const int row = blockIdx.x;
    const int t = threadIdx.x;
    const size_t off = (size_t)row * 256 + t;
    const float4 a = ((const float4*)p0)[off];
    const float4 c = ((const float4*)p1)[off];
    const float4 d = ((const float4*)p2)[off];
    const float4 e = ((const float4*)p3)[off];
    const float4 z = ((const float4*)Z)[off];
    float4 v;
    v.x = a.x + c.x + d.x + e.x + z.x;
    v.y = a.y + c.y + d.y + e.y + z.y;
    v.z = a.z + c.z + d.z + e.z + z.z;
    v.w = a.w + c.w + d.w + e.w + z.w;
    ((float4*)Z1)[off] = v;
    float s = v.x + v.y + v.z + v.w;
    float ss = v.x * v.x + v.y * v.y + v.z * v.z + v.w * v.w;
#pragma unroll
    for (int o = 1; o < 64; o <<= 1) {
        s += __shfl_xor(s, o);
        ss += __shfl_xor(ss, o);
    }
    __shared__ float rs[4], rss[4];
    const int wave = t >> 6, lane = t & 63;
    if (lane == 0) { rs[wave] = s; rss[wave] = ss; }
    __syncthreads();
    const float tot = rs[0] + rs[1] + rs[2] + rs[3];
    const float totss = rss[0] + rss[1] + rss[2] + rss[3];
    const float mu = tot * (1.0f / 1024.0f);
    const float var = totss * (1.0f / 1024.0f) - mu * mu;
    const float rstd = rsqrtf(var + 1e-5f);
    const float4 g4 = ((const float4*)gam)[t];
    const float4 b4 = ((const float4*)bet)[t];
    ushort4 o;
    o.x = f2bf((v.x - mu) * rstd * g4.x + b4.x);
    o.y = f2bf((v.y - mu) * rstd * g4.y + b4.y);
    o.z = f2bf((v.z - mu) * rstd * g4.z + b4.z);
    o.w = f2bf((v.w - mu) * rstd * g4.w + b4.w);
    ((ushort4*)(y + (size_t)row * 1024))[t] = o;
}

// ---- final combine: out = p0 + p1 + bias + Z1 ----
__global__ __launch_bounds__(256) void out_comb(const float* __restrict__ p0,
                                                const float* __restrict__ p1,
                                                const float* __restrict__ bias,
                                                const float* __restrict__ Z1,
                                                float* __restrict__ out) {
    int i = blockIdx.x * 256 + threadIdx.x;   // 1048576 float4s
    float4 a = ((const float4*)p0)[i];
    float4 c = ((const float4*)p1)[i];
    float4 z = ((const float4*)Z1)[i];
    float4 b = ((const float4*)bias)[i & 255];
    float4 o;
    o.x = a.x + c.x + z.x + b.x; o.y = a.y + c.y + z.y + b.y;
    o.z = a.z + c.z + z.z + b.z; o.w = a.w + c.w + z.w + b.w;
    ((float4*)out)[i] = o;
}

// ---------------- GEMM: C[M,N] = A[M,K-slice] @ Bt[N,K-slice]^T ----------------
// 128x128 tile, BK=32. ldk = row stride; K = slice length; slice start = z*K.
// EPI 0: +pbias; region: 0 -> f32 Vsc(out0), 1 -> Q bf16(out1), 2 -> K bf16(out2)
// EPI 2: +bias, relu, write bf16 out0
// EPI 4: raw f32 partial -> (z<2 ? out0 : out1) + (z&1)*M*N
template <int EPI>
__global__ __launch_bounds__(256, 3) void gemm_bt(const u16* __restrict__ A,
                                                  const u16* __restrict__ Bt,
                                                  const float* __restrict__ bias,
                                                  void* __restrict__ out0,
                                                  void* __restrict__ out1,
                                                  void* __restrict__ out2,
                                                  int M, int N, int K, int ldk) {
    __shared__ __align__(16) u16 As[128 * 32];
    __shared__ __align__(16) u16 Bs[128 * 32];
    const int tid = threadIdx.x;
    const int wave = tid >> 6, lane = tid & 63;
    const int lhi = lane >> 4, llo = lane & 15;
    const int bx = blockIdx.x, by = blockIdx.y;
    const int kz = blockIdx.z * K;

    const int arow = wave * 32 + (lane >> 2);
    const int acol = (lane & 3) * 8;
    const u16* gA = A + (size_t)(by * 128 + arow) * ldk + kz + acol;
    const u16* gB = Bt + (size_t)(bx * 128 + arow) * ldk + kz + acol;
    u16* lA = As + wave * 1024 + lane * 8;
    u16* lB = Bs + wave * 1024 + lane * 8;

    const int wr = wave >> 1, wc = wave & 1;
    const f32x4 zero = {0.f, 0.f, 0.f, 0.f};
    f32x4 acc[4][4];
#pragma unroll
    for (int i = 0; i < 4; i++)
#pragma unroll
        for (int j = 0; j < 4; j++) acc[i][j] = zero;

    for (int k0 = 0; k0 < K; k0 += 32) {
        __syncthreads();
        gl_lds16(gA, lA);
        gl_lds16(gA + 16 * (size_t)ldk, lA + 512);
        gl_lds16(gB, lB);
        gl_lds16(gB + 16 * (size_t)ldk, lB + 512);
        gA += 32; gB += 32;
        __syncthreads();
        bf16x8 af[4], bfr[4];
#pragma unroll
        for (int i = 0; i < 4; i++)
            af[i] = *(const bf16x8*)(As + (wr * 64 + i * 16 + llo) * 32 + lhi * 8);
#pragma unroll
        for (int j = 0; j < 4; j++)
            bfr[j] = *(const bf16x8*)(Bs + (wc * 64 + j * 16 + llo) * 32 + lhi * 8);
#pragma unroll
        for (int i = 0; i < 4; i++)
#pragma unroll
            for (int j = 0; j < 4; j++)
                acc[i][j] = __builtin_amdgcn_mfma_f32_16x16x32_bf16(af[i], bfr[j], acc[i][j], 0, 0, 0);
    }

    const int rbase = by * 128 + wr * 64 + lhi * 4;
    const int cbase = bx * 128 + wc * 64 + llo;
    float* pout = nullptr;
    if constexpr (EPI == 4) {
        pout = (blockIdx.z < 2) ? ((float*)out0 + (size_t)blockIdx.z * M * N)
                                : ((float*)out1 + (size_t)(blockIdx.z - 2) * M * N);
    }
#pragma unroll
    for (int i = 0; i < 4; i++) {
#pragma unroll
        for (int j = 0; j < 4; j++) {
#pragma unroll
            for (int r = 0; r < 4; r++) {
                const int row = rbase + i * 16 + r;
                const int col = cbase + j * 16;
                float v = acc[i][j][r];
                if constexpr (EPI == 0) {
                    v += bias[col];
                    const int region = col >> 10;   // uniform per block
                    const int c = col & 1023;       // h*64 + t
                    const int b = row >> 11, n = row & 2047;
                    if (region == 0) {
                        ((float*)out0)[(size_t)row * 1024 + c] = v;  // Vsc f32
                    } else {
                        const int h = c >> 6, t = c & 63;
                        u16* dst = (region == 1) ? (u16*)out1 : (u16*)out2;
                        dst[(((size_t)(b * 16 + h)) * 2048 + n) * 64 + t] = f2bf(v);
                    }
                } else if constexpr (EPI == 2) {
                    v += bias[col];
                    v = v > 0.f ? v : 0.f;
                    ((u16*)out0)[(size_t)row * N + col] = f2bf(v);
                } else {
                    pout[(size_t)row * N + col] = v;
                }
            }
        }
    }
}

// ---------------- V transpose: Vsc f32 [B*N][1024] -> Vt bf16 [BH][64][2048] --
__global__ __launch_bounds__(256) void vtrans(const float* __restrict__ Vsc,
                                              u16* __restrict__ Vt) {
    __shared__ u16 Ts[64 * 72];
    const int nt = blockIdx.x;  // n-tile (0..31)
    const int bh = blockIdx.y;  // 0..31
    const int b = bh >> 4, h = bh & 15;
    const int t = threadIdx.x;
    const int n0 = nt * 64;
    const int nr = t >> 2;
    const int dq = (t & 3) * 16;
    const float* src = Vsc + ((size_t)(b * 2048 + n0 + nr)) * 1024 + h * 64 + dq;
    float4 v0 = ((const float4*)src)[0];
    float4 v1 = ((const float4*)src)[1];
    float4 v2 = ((const float4*)src)[2];
    float4 v3 = ((const float4*)src)[3];
    u16* c0 = Ts + nr;
    c0[(dq + 0) * 72]  = f2bf(v0.x); c0[(dq + 1) * 72]  = f2bf(v0.y);
    c0[(dq + 2) * 72]  = f2bf(v0.z); c0[(dq + 3) * 72]  = f2bf(v0.w);
    c0[(dq + 4) * 72]  = f2bf(v1.x); c0[(dq + 5) * 72]  = f2bf(v1.y);
    c0[(dq + 6) * 72]  = f2bf(v1.z); c0[(dq + 7) * 72]  = f2bf(v1.w);
    c0[(dq + 8) * 72]  = f2bf(v2.x); c0[(dq + 9) * 72]  = f2bf(v2.y);
    c0[(dq + 10) * 72] = f2bf(v2.z); c0[(dq + 11) * 72] = f2bf(v2.w);
    c0[(dq + 12) * 72] = f2bf(v3.x); c0[(dq + 13) * 72] = f2bf(v3.y);
    c0[(dq + 14) * 72] = f2bf(v3.z); c0[(dq + 15) * 72] = f2bf(v3.w);
    __syncthreads();
    const int d = t >> 2, n8 = (t & 3) * 16;
    bf16x8 o0 = *(const bf16x8*)(Ts + d * 72 + n8);
    bf16x8 o1 = *(const bf16x8*)(Ts + d * 72 + n8 + 8);
    u16* dst = Vt + ((size_t)bh * 64 + d) * 2048 + n0 + n8;
    *(bf16x8*)dst = o0;
    *(bf16x8*)(dst + 8) = o1;
}

// ---------------- fused flash-style attention v4 ----------------
// grid 1024, id = hh*64 + b*32 + qt. q-tile 64, m-tile 64, 4 blocks/CU.
__global__ __launch_bounds__(256, 4) void attn_fused4(const u16* __restrict__ Qg,
                                                      const u16* __restrict__ Kg,
                                                      const u16* __restrict__ Vt,
                                                      const unsigned* __restrict__ Mp,
                                                      u16* __restrict__ attnL) {
    __shared__ __align__(16) u16 Qs[64 * 64];
    __shared__ __align__(16) u16 Ks[64 * 64];
    __shared__ __align__(16) u16 Vs[64 * 64];   // [d][m]
    __shared__ __align__(16) u16 Ps[64 * 72];   // padded rows
    const int tid = threadIdx.x, wave = tid >> 6, lane = tid & 63;
    const int lhi = lane >> 4, llo = lane & 15;
    const int id = blockIdx.x;
    const int hh = id >> 6, rem = id & 63;
    const int b = rem >> 5, qt = rem & 31;
    const int bh = b * 16 + hh;
    const int q0 = qt * 64;
    const int l3 = lane >> 3, l7 = lane & 7;
    const int swcol = (l7 ^ (l3 & 7)) * 8;   // swizzled source column (u16)

    // stage Q tile (64 rows) once
#pragma unroll
    for (int s = 0; s < 2; s++) {
        const int row = wave * 16 + s * 8 + l3;
        gl_lds16(Qg + ((size_t)bh * 2048 + q0 + row) * 64 + swcol,
                 Qs + wave * 1024 + s * 512 + lane * 8);
    }

    const unsigned* Mpb = Mp + (size_t)b * 2048 * 2048;
    int midx[4];
#pragma unroll
    for (int r = 0; r < 4; r++)
        midx[r] = (q0 + wave * 16 + lhi * 4 + r) * 2048 + llo;

    const f32x4 zero = {0.f, 0.f, 0.f, 0.f};
    f32x4 accO[4];
    float lsum[4];
#pragma unroll
    for (int j = 0; j < 4; j++) accO[j] = zero;
#pragma unroll
    for (int r = 0; r < 4; r++) lsum[r] = 0.f;

    const float CS = 0.125f * 1.4426950f;
    const int pb0 = (wave * 16 + lhi * 4) * 72 + llo;

    for (int m0 = 0; m0 < 2048; m0 += 64) {
        __syncthreads();
        // stage K[m0..m0+64) and Vt[:, m0..m0+64) (swizzled)
#pragma unroll
        for (int s = 0; s < 2; s++) {
            const int row = wave * 16 + s * 8 + l3;
            gl_lds16(Kg + ((size_t)bh * 2048 + m0 + row) * 64 + swcol,
                     Ks + wave * 1024 + s * 512 + lane * 8);
            gl_lds16(Vt + ((size_t)bh * 64 + row) * 2048 + m0 + swcol,
                     Vs + wave * 1024 + s * 512 + lane * 8);
        }
        // mask loads ride the same latency window; ready at the barrier
        unsigned mv[4][4];
#pragma unroll
        for (int r = 0; r < 4; r++)
#pragma unroll
            for (int j = 0; j < 4; j++) mv[r][j] = Mpb[midx[r] + m0 + j * 16];
        __syncthreads();

        // S = Q K^T  (wave's 16 q-rows x 64 m-cols)
        f32x4 sacc[4];
#pragma unroll
        for (int j = 0; j < 4; j++) sacc[j] = zero;
#pragma unroll
        for (int kk = 0; kk < 2; kk++) {
            const bf16x8 aq = *(const bf16x8*)(Qs + sw8(wave * 16 + llo, kk * 4 + lhi));
#pragma unroll
            for (int j = 0; j < 4; j++) {
                const bf16x8 bk = *(const bf16x8*)(Ks + sw8(j * 16 + llo, kk * 4 + lhi));
                sacc[j] = __builtin_amdgcn_mfma_f32_16x16x32_bf16(aq, bk, sacc[j], 0, 0, 0);
            }
        }

        // P = exp2(S*CS + nm) * pm ; l += exp (unmasked denominator)
#pragma unroll
        for (int j = 0; j < 4; j++)
#pragma unroll
            for (int r = 0; r < 4; r++) {
                const unsigned u = mv[r][j];
                const float nm = __uint_as_float(u << 16);
                const float pm = __uint_as_float(u & 0xFFFF0000u);
                const float e = exp2f(fmaf(sacc[j][r], CS, nm));
                lsum[r] += e;
                const float p = e * pm;
                Ps[pb0 + r * 72 + j * 16] = (u16)(__float_as_uint(p) >> 16);  // truncate
            }

        // O += P @ V  (Ps rows wave-private)
#pragma unroll
        for (int kk = 0; kk < 2; kk++) {
            const bf16x8 ap = *(const bf16x8*)(Ps + (wave * 16 + llo) * 72 + kk * 32 + lhi * 8);
#pragma unroll
            for (int jd = 0; jd < 4; jd++) {
                const bf16x8 bv = *(const bf16x8*)(Vs + sw8(jd * 16 + llo, kk * 4 + lhi));
                accO[jd] = __builtin_amdgcn_mfma_f32_16x16x32_bf16(ap, bv, accO[jd], 0, 0, 0);
            }
        }
    }

    // reduce l over the 16 llo-lanes, epilogue leaky_relu(O/l)
#pragma unroll
    for (int r = 0; r < 4; r++) {
#pragma unroll
        for (int o = 1; o < 16; o <<= 1) lsum[r] += __shfl_xor(lsum[r], o);
        lsum[r] = 1.0f / lsum[r];
    }
#pragma unroll
    for (int jd = 0; jd < 4; jd++)
#pragma unroll
        for (int r = 0; r < 4; r++) {
            float v = accO[jd][r] * lsum[r];
            v = v >= 0.f ? v : 0.01f * v;
            const int q = q0 + wave * 16 + lhi * 4 + r;
            attnL[((size_t)b * 2048 + q) * 1024 + hh * 64 + jd * 16 + llo] = f2bf(v);
        }
}

// ---------------- launcher ----------------
extern "C" void kernel_launch(void* const* d_in, const int* in_sizes, int n_in,
                              void* d_out, int out_size, void* d_ws, size_t ws_size,
                              hipStream_t stream) {
    const float* Z     = (const float*)d_in[0];
    const float* nmask = (const float*)d_in[1];
    const float* pmask = (const float*)d_in[2];
    const float* ln1_g = (const float*)d_in[3];
    const float* ln1_b = (const float*)d_in[4];
    const float* qkv_w = (const float*)d_in[5];
    const float* qkv_b = (const float*)d_in[6];
    const float* o_w   = (const float*)d_in[7];
    const float* ln2_g = (const float*)d_in[8];
    const float* ln2_b = (const float*)d_in[9];
    const float* p1_w  = (const float*)d_in[10];
    const float* p1_b  = (const float*)d_in[11];
    const float* p2_w  = (const float*)d_in[12];
    const float* p2_b  = (const float*)d_in[13];
    float* out = (float*)d_out;

    char* w = (char*)d_ws;
    auto take = [&](size_t bytes) -> char* {
        char* p = w;
        w += (bytes + 255) & ~(size_t)255;
        return p;
    };
    u16* qkvW   = (u16*)take((size_t)3072 * 1024 * 2);
    u16* oW     = (u16*)take((size_t)1024 * 1024 * 2);
    u16* p1W    = (u16*)take((size_t)4096 * 1024 * 2);
    u16* p2W    = (u16*)take((size_t)1024 * 4096 * 2);
    u16* Zn     = (u16*)take((size_t)4096 * 1024 * 2);   // reused for Zn2
    u16* Qb     = (u16*)take((size_t)32 * 2048 * 64 * 2);
    u16* Kb     = (u16*)take((size_t)32 * 2048 * 64 * 2);
    u16* Vt     = (u16*)take((size_t)32 * 64 * 2048 * 2);
    u16* attnL  = (u16*)take((size_t)4096 * 1024 * 2);
    float* Z1   = (float*)take((size_t)4096 * 1024 * 4);
    u16* hbuf   = (u16*)take((size_t)4096 * 4096 * 2);   // 33.55 MB
    unsigned* Mp = (unsigned*)take((size_t)2 * 2048 * 2048 * 4);  // 33.55 MB
    float* pbias = (float*)take((size_t)3072 * 4);
    float* Vsc    = (float*)hbuf;          // alias: dead before hbuf written
    float* part01 = (float*)Mp;            // alias: Mp dead after attention
    float* part23 = (float*)hbuf;          // alias: hbuf dead during o-proj

    // merged prep (casts + bias permute + mask pack)
    prep_all<<<dim3(20481), 256, 0, stream>>>(qkv_w, o_w, p1_w, p2_w, qkv_b, nmask, pmask,
                                              qkvW, oW, p1W, p2W, pbias, Mp);
    // LN1
    ln_bf16<<<dim3(4096), 256, 0, stream>>>(Z, ln1_g, ln1_b, Zn);
    // QKV projection: V -> f32 scratch, Q/K -> bf16 [BH][N][64]
    gemm_bt<0><<<dim3(24, 32), 256, 0, stream>>>(Zn, qkvW, pbias, Vsc, Qb, Kb, 4096, 3072, 1024, 1024);
    // V transpose -> Vt [BH][64][2048]
    vtrans<<<dim3(32, 32), 256, 0, stream>>>(Vsc, Vt);
    // attention (4 blocks/CU)
    attn_fused4<<<dim3(1024), 256, 0, stream>>>(Qb, Kb, Vt, Mp, attnL);
    // o-projection, split-K=4 -> f32 partials (p0,p1 in Mp; p2,p3 in hbuf)
    gemm_bt<4><<<dim3(8, 32, 4), 256, 0, stream>>>(attnL, oW, nullptr, part01, part23, nullptr,
                                                   4096, 1024, 256, 1024);
    // 4-way combine + residual + LN2 (writes Z1 and Zn)
    ln2_comb4<<<dim3(4096), 256, 0, stream>>>(part01, part01 + (size_t)4096 * 1024,
                                              part23, part23 + (size_t)4096 * 1024,
                                              Z, ln2_g, ln2_b, Z1, Zn);
    // MLP up + relu -> hbuf (bf16)
    gemm_bt<2><<<dim3(32, 32), 256, 0, stream>>>(Zn, p1W, p1_b, hbuf, nullptr, nullptr,
                                                 4096, 4096, 1024, 1024);
    // MLP down, split-K=2 -> f32 partials in Mp
    gemm_bt<4><<<dim3(8, 32, 2), 256, 0, stream>>>(hbuf, p2W, nullptr, part01, nullptr, nullptr,
                                                   4096, 1024, 2048, 4096);
    // final combine -> out
    out_comb<<<dim3(4096), 256, 0, stream>>>(part01, part01 + (size_t)4096 * 1024, p2_b, Z1, out);
}